// Round 25
// baseline (296.110 us; speedup 1.0000x reference)
//
#include <hip/hip_runtime.h>
#include <math.h>

#define B_ 4
#define N_ 1024
#define C_ 1024
#define NH_ 16
#define HD_ 64
#define PP_ 128
#define LOG2E 1.4426950408889634f

typedef __bf16 bf16;
typedef __attribute__((ext_vector_type(8))) __bf16 bf16x8;
typedef __attribute__((ext_vector_type(4))) __bf16 bf16x4;
typedef __attribute__((ext_vector_type(4))) float f32x4;

#define MFMA_BF16(a, b, c) __builtin_amdgcn_mfma_f32_16x16x32_bf16((a), (b), (c), 0, 0, 0)

__device__ __forceinline__ float gelu_f(float x) {
    return 0.5f * x * (1.0f + erff(x * 0.70710678118654752f));
}

__device__ __forceinline__ void gload16(const void* g, void* l) {
    __builtin_amdgcn_global_load_lds(
        (const __attribute__((address_space(1))) void*)g,
        (__attribute__((address_space(3))) void*)l, 16, 0, 0);
}

// stage a 64-row x 128B tile into LDS, XOR-swizzled source, 512 threads (1 chunk each)
__device__ __forceinline__ void stage64(const bf16* __restrict__ g, int pitchB,
                                        bf16* lds, int t) {
    int row = t >> 3, c = t & 7;
    const char* src = (const char*)g + (size_t)row * pitchB + ((c ^ (row & 7)) << 4);
    gload16(src, lds + (size_t)(t & 448) * 8);
}

// stage a 32-row x 128B tile (ext: 64 k-rows x 64B packed 2-per-LDS-row), 256 of 512 threads
__device__ __forceinline__ void stage32(const bf16* __restrict__ g, bf16* lds, int t) {
    if (t < 256) {
        int row = t >> 3, c = t & 7;
        const char* src = (const char*)g + (size_t)row * 128 + ((c ^ (row & 7)) << 4);
        gload16(src, lds + (size_t)(t & 192) * 8);
    }
}

__device__ __forceinline__ bf16x8 lds8_swz(const bf16* lds, int row, int colb) {
    return *reinterpret_cast<const bf16x8*>(
        (const char*)lds + row * 128 + (colb ^ ((row & 7) << 4)));
}

// 256B-row variant (for pl23m tiles)
__device__ __forceinline__ bf16x8 lds8_swz256(const bf16* lds, int row, int colb) {
    return *reinterpret_cast<const bf16x8*>(
        (const char*)lds + row * 256 + (colb ^ ((row & 7) << 4)));
}

// read 16B of ext row kr (64B rows packed 2-per-LDS-row), chunk g in 0..3
__device__ __forceinline__ bf16x8 lds8_ke(const bf16* lds, int kr, int g) {
    int r = kr >> 1;
    int ch = ((kr & 1) * 4 + g) ^ (r & 7);
    return *reinterpret_cast<const bf16x8*>((const char*)lds + r * 128 + (ch << 4));
}

// ============ transpose-cast job table (10 jobs) ============
struct TJobs {
    const float* src[11];
    bf16* dst[11];
    int K[11];
    int N[11];
    int base[12];   // prefix tile offsets; base[10] = total tiles
};

// ===== merged preamble: tcast | cast x | cast w_cp | cast w_sp | tables | bscg | bsc | pl1
__global__ __launch_bounds__(256) void pre_k(
    TJobs J, const float* __restrict__ x, bf16* __restrict__ xb,
    const float* __restrict__ w_cp, bf16* __restrict__ wcpB,
    const float* __restrict__ w_sp, bf16* __restrict__ wspB,
    const float* __restrict__ rel_table, float* __restrict__ relT, float2* __restrict__ rt,
    const float* __restrict__ b_cp, const float* __restrict__ gfw1,
    const float* __restrict__ gfb1, float* __restrict__ bscg,
    const float* __restrict__ b_sp, const float* __restrict__ w_cq, float* __restrict__ bsc,
    const float* __restrict__ pl,
    const float* __restrict__ w1, const float* __restrict__ b1,
    const float* __restrict__ dw1, const float* __restrict__ db1,
    const float* __restrict__ dw2, const float* __restrict__ db2,
    bf16* __restrict__ h1b, float* __restrict__ ds, float* __restrict__ dn)
{
    __shared__ float tl[32][33];
    __shared__ float plr[6];
    __shared__ float dh[64];
    __shared__ float red[4][64];
    const int t = threadIdx.x;
    const int bid = blockIdx.x;
    const int ntc = J.base[10];
    if (bid < ntc) {
        int tile = bid;
        int j = 0;
        while (j + 1 < 10 && tile >= J.base[j + 1]) ++j;
        tile -= J.base[j];
        const int Kd = J.K[j], Nd = J.N[j];
        const int ntx = Nd >> 5;
        const int n0 = (tile % ntx) * 32, k0 = (tile / ntx) * 32;
        const int tx = t & 31, ty = t >> 5;
        const float* src = J.src[j];
        bf16* dst = J.dst[j];
        #pragma unroll
        for (int r = 0; r < 4; ++r) {
            int kk = ty + r * 8;
            tl[kk][tx] = src[(size_t)(k0 + kk) * Nd + n0 + tx];
        }
        __syncthreads();
        #pragma unroll
        for (int r = 0; r < 4; ++r) {
            int nn = ty + r * 8;
            dst[(size_t)(n0 + nn) * Kd + k0 + tx] = (bf16)tl[tx][nn];
        }
    } else if (bid < ntc + 4096) {
        int g = (bid - ntc) * 256 + t;
        float4 v = reinterpret_cast<const float4*>(x)[g];
        bf16x4 o = {(bf16)v.x, (bf16)v.y, (bf16)v.z, (bf16)v.w};
        reinterpret_cast<bf16x4*>(xb)[g] = o;
    } else if (bid < ntc + 4096 + 256) {
        int g = (bid - ntc - 4096) * 256 + t;
        float4 v = reinterpret_cast<const float4*>(w_cp)[g];
        bf16x4 o = {(bf16)v.x, (bf16)v.y, (bf16)v.z, (bf16)v.w};
        reinterpret_cast<bf16x4*>(wcpB)[g] = o;
    } else if (bid < ntc + 4096 + 512) {
        int g = (bid - ntc - 4096 - 256) * 256 + t;
        float4 v = reinterpret_cast<const float4*>(w_sp)[g];
        bf16x4 o = {(bf16)v.x, (bf16)v.y, (bf16)v.z, (bf16)v.w};
        reinterpret_cast<bf16x4*>(wspB)[g] = o;
    } else if (bid < ntc + 4096 + 512 + 377) {
        int g = (bid - ntc - 4096 - 512) * 256 + t;
        if (g < 32768) {
            const int n = g >> 5, i = g & 31;
            const float inv = powf(10000.0f, -(float)(2 * i) / 64.0f);
            const float ang = (float)n * inv;
            rt[g] = make_float2(cosf(ang), sinf(ang));
        } else {
            int i = g - 32768;
            if (i < 16 * 3969) {
                int h = i / 3969, idx = i - h * 3969;
                relT[i] = rel_table[idx * 16 + h];
            }
        }
    } else if (bid < ntc + 4096 + 512 + 377 + 16) {
        // bscg[c] = gfb1[c] + sum_{j<1024} b_cp[j] * gfw1[j][c]
        const int pb = bid - ntc - 4096 - 512 - 377;
        const int c = pb * 64 + (t & 63);
        const int js = t >> 6;
        float a = 0.f;
        #pragma unroll 8
        for (int j = js * 256; j < js * 256 + 256; ++j)
            a = fmaf(b_cp[j], gfw1[(size_t)j * 1024 + c], a);
        red[js][t & 63] = a;
        __syncthreads();
        if (t < 64) {
            int cc = pb * 64 + t;
            bscg[cc] = red[0][t] + red[1][t] + red[2][t] + red[3][t] + gfb1[cc];
        }
    } else if (bid < ntc + 4096 + 512 + 377 + 32) {
        // bsc[c] = sum_{j<1024} b_sp[j] * w_cq[j][c]
        const int pb = bid - ntc - 4096 - 512 - 377 - 16;
        const int c = pb * 64 + (t & 63);
        const int js = t >> 6;
        float a = 0.f;
        #pragma unroll 8
        for (int j = js * 256; j < js * 256 + 256; ++j)
            a = fmaf(b_sp[j], w_cq[(size_t)j * 1024 + c], a);
        red[js][t & 63] = a;
        __syncthreads();
        if (t < 64) {
            int cc = pb * 64 + t;
            bsc[cc] = red[0][t] + red[1][t] + red[2][t] + red[3][t];
        }
    } else {
        const int pb = bid - ntc - 4096 - 512 - 377 - 32;
        #pragma unroll 1
        for (int rr = 0; rr < 4; ++rr) {
            const int row = pb * 4 + rr;
            if (t < 6) plr[t] = pl[(size_t)row * 6 + t];
            __syncthreads();
            {
                float a = b1[t];
                #pragma unroll
                for (int j = 0; j < 6; ++j) a = fmaf(plr[j], w1[j * 256 + t], a);
                h1b[(size_t)row * 256 + t] = (bf16)gelu_f(a);
            }
            if (t < 64) {
                float d = db1[t];
                #pragma unroll
                for (int j = 0; j < 6; ++j) d = fmaf(plr[j], dw1[j * 64 + t], d);
                dh[t] = gelu_f(d);
            }
            if (t == 0) {
                float xx = plr[0], yy = plr[1], zz = plr[2];
                float nrm = fmaxf(sqrtf(xx * xx + yy * yy + zz * zz), 1e-12f);
                dn[(size_t)row * 4 + 0] = xx / nrm;
                dn[(size_t)row * 4 + 1] = yy / nrm;
                dn[(size_t)row * 4 + 2] = zz / nrm;
                dn[(size_t)row * 4 + 3] = 0.f;
            }
            __syncthreads();
            if (t < 16) {
                float d = db2[t];
                #pragma unroll 8
                for (int j = 0; j < 64; ++j) d = fmaf(dh[j], dw2[j * 16 + t], d);
                ds[(size_t)row * 16 + t] = tanhf(d);
            }
            __syncthreads();
        }
    }
}

// ============ GEMM job descriptor ============
struct GJob {
    const bf16* A; const bf16* A2; const bf16* Bt; const bf16* Bt2;
    const float* bias; const float* resid;
    void* out0; void* out1; void* out2;
    const float2* rtab;
    int N, K, K1A, K1B, epi, act_gelu, gx;
    float scale;
};

// ============ MFMA GEMM body, 128x64 tile, BK=64, 2-phase double-buffered ============
__device__ __forceinline__ void gemm_body(const GJob& P, int bx, int by, char* smem)
{
    const bf16* A = P.A; const bf16* A2 = P.A2;
    const bf16* Bt = P.Bt; const bf16* Bt2 = P.Bt2;
    const float* bias = P.bias; const float* resid = P.resid;
    void* out0 = P.out0; void* out1 = P.out1; void* out2 = P.out2;
    const float2* rtab = P.rtab;
    const int N = P.N, K = P.K, K1A = P.K1A, K1B = P.K1B;
    const int epi = P.epi, act_gelu = P.act_gelu;
    const float scale = P.scale;

    bf16 (*As)[128 * 64] = (bf16(*)[128 * 64])smem;
    bf16 (*Bs)[64 * 64]  = (bf16(*)[64 * 64])(smem + 32768);
    const int t = threadIdx.x;
    const int w = t >> 6, lane = t & 63;
    const int row0 = by * 128, col0 = bx * 64;
    const int wm = w >> 1, wn = w & 1;
    const int K2A = K - K1A, K2B = K - K1B;
    f32x4 acc[4][2];
    #pragma unroll
    for (int mi = 0; mi < 4; ++mi)
        #pragma unroll
        for (int ni = 0; ni < 2; ++ni)
            acc[mi][ni] = (f32x4){0.f, 0.f, 0.f, 0.f};

    #define STAGE_AB64(k0, buf)                                                \
        {                                                                      \
            const bf16* abase; int apitch;                                     \
            if ((k0) < K1A) { abase = A + (k0); apitch = K1A; }                \
            else            { abase = A2 + ((k0) - K1A); apitch = K2A; }       \
            _Pragma("unroll")                                                  \
            for (int r = 0; r < 4; ++r) {                                      \
                int c = r * 256 + t;                                           \
                int rr = c >> 3, cc = c & 7;                                   \
                const char* srca = (const char*)(abase + (size_t)(row0 + rr) * apitch) \
                                   + ((cc ^ (rr & 7)) << 4);                   \
                gload16(srca, As[buf] + (size_t)(r * 256 + (t & 192)) * 8);    \
            }                                                                  \
            const bf16* bbase; int bpitch;                                     \
            if ((k0) < K1B) { bbase = Bt + (k0); bpitch = K1B; }               \
            else            { bbase = Bt2 + ((k0) - K1B); bpitch = K2B; }      \
            _Pragma("unroll")                                                  \
            for (int r = 0; r < 2; ++r) {                                      \
                int c = r * 256 + t;                                           \
                int rr = c >> 3, cc = c & 7;                                   \
                const char* srcb = (const char*)(bbase + (size_t)(col0 + rr) * bpitch) \
                                   + ((cc ^ (rr & 7)) << 4);                   \
                gload16(srcb, Bs[buf] + (size_t)(r * 256 + (t & 192)) * 8);    \
            }                                                                  \
        }

    int cur = 0;
    const int nk = K >> 6;
    STAGE_AB64(0, 0);
    __syncthreads();
    for (int kk = 0; kk < nk; ++kk) {
        if (kk + 1 < nk) STAGE_AB64((kk + 1) * 64, cur ^ 1);
        bf16x8 af[4][2], bfv[2][2];
        #pragma unroll
        for (int mi = 0; mi < 4; ++mi)
            #pragma unroll
            for (int kh = 0; kh < 2; ++kh)
                af[mi][kh] = lds8_swz(As[cur], wm * 64 + mi * 16 + (lane & 15),
                                      kh * 64 + (lane >> 4) * 16);
        #pragma unroll
        for (int ni = 0; ni < 2; ++ni)
            #pragma unroll
            for (int kh = 0; kh < 2; ++kh)
                bfv[ni][kh] = lds8_swz(Bs[cur], wn * 32 + ni * 16 + (lane & 15),
                                       kh * 64 + (lane >> 4) * 16);
        #pragma unroll
        for (int kh = 0; kh < 2; ++kh)
            #pragma unroll
            for (int mi = 0; mi < 4; ++mi)
                #pragma unroll
                for (int ni = 0; ni < 2; ++ni)
                    acc[mi][ni] = MFMA_BF16(af[mi][kh], bfv[ni][kh], acc[mi][ni]);
        __syncthreads();
        cur ^= 1;
    }
    #undef STAGE_AB64

    #pragma unroll
    for (int mi = 0; mi < 4; ++mi) {
        #pragma unroll
        for (int ni = 0; ni < 2; ++ni) {
            const int col = col0 + wn * 32 + ni * 16 + (lane & 15);
            if (epi <= 1 || epi == 5) {
                const float bv = bias ? bias[col] : 0.f;
                #pragma unroll
                for (int j = 0; j < 4; ++j) {
                    const int row = row0 + wm * 64 + mi * 16 + (lane >> 4) * 4 + j;
                    float v = acc[mi][ni][j] + bv;
                    if (act_gelu) v = gelu_f(v);
                    if (epi == 0) {
                        if (resid) v += resid[(size_t)row * N + col];
                        ((float*)out0)[(size_t)row * N + col] = v;
                    } else if (epi == 1) {
                        ((bf16*)out0)[(size_t)row * N + col] = (bf16)v;
                    } else {
                        ((float*)out0)[(size_t)row * N + col] = v;
                        ((bf16*)out1)[(size_t)row * N + col] = (bf16)v;
                    }
                }
            } else if (epi == 2) {
                const int reg = col >> 10;         // 0=q 1=k 2=v
                const int h = (col >> 6) & 15, d = col & 63;
                if (reg <= 1) {
                    bf16* dst = reg == 0 ? (bf16*)out0 : (bf16*)out1;
                    const float sc = reg == 0 ? scale : 1.0f;
                    #pragma unroll
                    for (int j = 0; j < 4; ++j) {
                        const int row = row0 + wm * 64 + mi * 16 + (lane >> 4) * 4 + j;
                        const int b = row >> 10, n = row & 1023;
                        float v = acc[mi][ni][j];
                        float pv = __shfl_xor(v, 1);
                        float2 cs = rtab[(n << 5) + (d >> 1)];
                        float o = (d & 1) == 0 ? v * cs.x - pv * cs.y
                                               : v * cs.x + pv * cs.y;
                        dst[((size_t)((b * 16 + h) * 1024 + n)) * 64 + d] = (bf16)(o * sc);
                    }
                } else {
                    bf16x4 o4;
                    #pragma unroll
                    for (int j = 0; j < 4; ++j) o4[j] = (bf16)acc[mi][ni][j];
                    const int row = row0 + wm * 64 + mi * 16 + (lane >> 4) * 4;
                    const int b = row >> 10, n = row & 1023;
                    *reinterpret_cast<bf16x4*>(
                        (bf16*)out2 + ((size_t)((b * 16 + h) * 64 + d)) * 1024 + n) = o4;
                }
            } else if (epi == 3 || epi == 6) {
                const int h = (col >> 6) & 15, d = col & 63;
                const float bv = bias ? bias[col] : 0.f;
                #pragma unroll
                for (int j = 0; j < 4; ++j) {
                    const int row = row0 + wm * 64 + mi * 16 + (lane >> 4) * 4 + j;
                    const int b = row >> 10, n = row & 1023;
                    float v = acc[mi][ni][j] + bv;
                    float pv = __shfl_xor(v, 1);
                    float2 cs = rtab[(n << 5) + (d >> 1)];
                    float o = (d & 1) == 0 ? v * cs.x - pv * cs.y
                                           : v * cs.x + pv * cs.y;
                    float sc = scale;
                    if (epi == 6) sc *= 1.0f + resid[(size_t)row * 16 + h];
                    ((bf16*)out0)[((size_t)((b * 16 + h) * 1024 + n)) * 64 + d] = (bf16)(o * sc);
                }
            } else if (epi == 7) {
                const int reg = col >> 10;         // 0=ck(rope) 1=cv(transposed)
                const int h = (col >> 6) & 15, d = col & 63;
                if (reg == 0) {
                    #pragma unroll
                    for (int j = 0; j < 4; ++j) {
                        const int row = row0 + wm * 64 + mi * 16 + (lane >> 4) * 4 + j;
                        const int b = row >> 10, n = row & 1023;
                        float v = acc[mi][ni][j];
                        float pv = __shfl_xor(v, 1);
                        float2 cs = rtab[(n << 5) + (d >> 1)];
                        float o = (d & 1) == 0 ? v * cs.x - pv * cs.y
                                               : v * cs.x + pv * cs.y;
                        ((bf16*)out0)[((size_t)((b * 16 + h) * 1024 + n)) * 64 + d] = (bf16)o;
                    }
                } else {
                    bf16x4 o4;
                    #pragma unroll
                    for (int j = 0; j < 4; ++j) o4[j] = (bf16)acc[mi][ni][j];
                    const int row = row0 + wm * 64 + mi * 16 + (lane >> 4) * 4;
                    const int b = row >> 10, n = row & 1023;
                    *reinterpret_cast<bf16x4*>(
                        (bf16*)out2 + ((size_t)((b * 16 + h) * 64 + d)) * 1024 + n) = o4;
                }
            } else {  // epi == 4: transposed head-major
                const int h = (col >> 6) & 15, d = col & 63;
                bf16x4 o4;
                #pragma unroll
                for (int j = 0; j < 4; ++j) o4[j] = (bf16)acc[mi][ni][j];
                const int row = row0 + wm * 64 + mi * 16 + (lane >> 4) * 4;
                const int b = row >> 10, n = row & 1023;
                *reinterpret_cast<bf16x4*>(
                    (bf16*)out0 + ((size_t)((b * 16 + h) * 64 + d)) * 1024 + n) = o4;
            }
        }
    }
}

// ============ plucker layers 2+3 body (uses 48KB smem) ============
__device__ __forceinline__ void pl23m_body(
    int bid, const bf16* __restrict__ h1, const bf16* __restrict__ w2T,
    const float* __restrict__ b2, const bf16* __restrict__ w3T, const float* __restrict__ b3,
    float* __restrict__ pp, bf16* __restrict__ ppb, char* smem)
{
    bf16* Am = (bf16*)smem;              // 16KB
    bf16* Wm = (bf16*)(smem + 16384);    // 32KB
    const int t = threadIdx.x, w = t >> 6, lane = t & 63;
    const int row0 = bid * 64;
    f32x4 acc[8];
    #pragma unroll
    for (int nt = 0; nt < 8; ++nt) acc[nt] = (f32x4){0.f, 0.f, 0.f, 0.f};

    for (int kc = 0; kc < 2; ++kc) {
        #pragma unroll
        for (int r = 0; r < 4; ++r) {
            int i = r * 256 + t;
            int row = i >> 4, c = i & 15;
            const char* src = (const char*)(h1 + (size_t)(row0 + row) * 256 + kc * 128)
                              + ((c ^ (row & 7)) << 4);
            gload16(src, Am + (size_t)(r * 256 + (t & 192)) * 8);
        }
        #pragma unroll
        for (int r = 0; r < 8; ++r) {
            int i = r * 256 + t;
            int row = i >> 4, c = i & 15;
            const char* src = (const char*)(w2T + (size_t)row * 256 + kc * 128)
                              + ((c ^ (row & 7)) << 4);
            gload16(src, Wm + (size_t)(r * 256 + (t & 192)) * 8);
        }
        __syncthreads();
        #pragma unroll
        for (int step = 0; step < 4; ++step) {
            bf16x8 af = lds8_swz256(Am, w * 16 + (lane & 15), step * 64 + (lane >> 4) * 16);
            #pragma unroll
            for (int nt = 0; nt < 8; ++nt) {
                bf16x8 bfv = lds8_swz256(Wm, nt * 16 + (lane & 15), step * 64 + (lane >> 4) * 16);
                acc[nt] = MFMA_BF16(af, bfv, acc[nt]);
            }
        }
        __syncthreads();
    }
    #pragma unroll
    for (int r = 0; r < 8; ++r) {
        int i = r * 256 + t;
        int row = i >> 4, c = i & 15;
        const char* src = (const char*)(w3T + (size_t)row * 128) + ((c ^ (row & 7)) << 4);
        gload16(src, Wm + (size_t)(r * 256 + (t & 192)) * 8);
    }
    #pragma unroll
    for (int nt = 0; nt < 8; ++nt) {
        const int col = nt * 16 + (lane & 15);
        const float bv = b2[col];
        #pragma unroll
        for (int j = 0; j < 4; ++j) {
            const int row = w * 16 + (lane >> 4) * 4 + j;
            const int byte = row * 256 + (((col * 2) & ~15) ^ ((row & 7) << 4)) + ((col * 2) & 15);
            *reinterpret_cast<bf16*>((char*)Am + byte) = (bf16)gelu_f(acc[nt][j] + bv);
        }
    }
    __syncthreads();
    f32x4 acc2[8];
    #pragma unroll
    for (int nt = 0; nt < 8; ++nt) acc2[nt] = (f32x4){0.f, 0.f, 0.f, 0.f};
    #pragma unroll
    for (int step = 0; step < 4; ++step) {
        bf16x8 af = lds8_swz256(Am, w * 16 + (lane & 15), step * 64 + (lane >> 4) * 16);
        #pragma unroll
        for (int nt = 0; nt < 8; ++nt) {
            bf16x8 bfv = lds8_swz256(Wm, nt * 16 + (lane & 15), step * 64 + (lane >> 4) * 16);
            acc2[nt] = MFMA_BF16(af, bfv, acc2[nt]);
        }
    }
    #pragma unroll
    for (int nt = 0; nt < 8; ++nt) {
        const int col = nt * 16 + (lane & 15);
        const float bv = b3[col];
        #pragma unroll
        for (int j = 0; j < 4; ++j) {
            const int row = row0 + w * 16 + (lane >> 4) * 4 + j;
            const float v = acc2[nt][j] + bv;
            pp[(size_t)row * 128 + col] = v;
            ppb[(size_t)row * 128 + col] = (bf16)v;
        }
    }
}

// ============ gb layer2 body (uses 32KB of smem) ============
__device__ __forceinline__ void gb2x_body(
    int bid, const bf16* __restrict__ h, const float* __restrict__ w2,
    const float* __restrict__ b2, const float* __restrict__ dn,
    const float* __restrict__ ds, const float* __restrict__ rdb,
    bf16* __restrict__ qe, bf16* __restrict__ ke, char* smem)
{
    float* w2s = (float*)smem;   // 32KB
    const int t = threadIdx.x;
    for (int i = t; i < 8192; i += 256) w2s[i] = w2[i];
    __syncthreads();
    const int row = bid * 16 + (t >> 4);
    const int hh = t & 15;
    const bf16* hr = h + (size_t)row * 512;
    float acc = b2[hh];
    #pragma unroll 8
    for (int j = 0; j < 512; ++j)
        acc = fmaf((float)hr[j], w2s[j * 16 + hh], acc);
    const float gbv = tanhf(acc);
    const int b = row >> 10, n = row & 1023;
    const float c1 = rdb[hh] * LOG2E * (1.0f + ds[(size_t)row * 16 + hh]);
    const float dx = dn[(size_t)row * 4], dy = dn[(size_t)row * 4 + 1], dz = dn[(size_t)row * 4 + 2];
    bf16x8 z = {};
    bf16x8 q0 = z, k0 = z;
    q0[0] = (bf16)(dx * c1); q0[1] = (bf16)(dy * c1); q0[2] = (bf16)(dz * c1); q0[3] = (bf16)1.0f;
    k0[0] = (bf16)dx; k0[1] = (bf16)dy; k0[2] = (bf16)dz; k0[3] = (bf16)(gbv * LOG2E);
    const size_t g = (size_t)(b * 16 + hh) * 1024 + n;
    bf16x8* qp = reinterpret_cast<bf16x8*>(qe + g * 32);
    bf16x8* kp = reinterpret_cast<bf16x8*>(ke + g * 32);
    qp[0] = q0; qp[1] = z; qp[2] = z; qp[3] = z;
    kp[0] = k0; kp[1] = z; kp[2] = z; kp[3] = z;
}

__global__ __launch_bounds__(256) void gemm_k(GJob P)
{
    __shared__ char smem[49152];
    gemm_body(P, blockIdx.x % P.gx, blockIdx.x / P.gx, smem);
}

// ===== wsc combine (0-127) || pl23m (128-191) || qkv (192-1727) ==
// small independent segments FIRST (R20/R21 lesson); wcg moved to step-5 launch.
__global__ __launch_bounds__(256) void qkvpl_k(GJob P, GJob Ps2,
    const bf16* __restrict__ h1, const bf16* __restrict__ w2T, const float* __restrict__ b2,
    const bf16* __restrict__ w3T, const float* __restrict__ b3,
    float* __restrict__ pp, bf16* __restrict__ ppb)
{
    __shared__ char smem[49152];
    if (blockIdx.x < 128) gemm_body(Ps2, blockIdx.x % Ps2.gx, blockIdx.x / Ps2.gx, smem);
    else if (blockIdx.x < 192) pl23m_body(blockIdx.x - 128, h1, w2T, b2, w3T, b3, pp, ppb, smem);
    else {
        int id = blockIdx.x - 192;
        gemm_body(P, id % P.gx, id / P.gx, smem);
    }
}

// ==== wcg combine (0-127) || gb2x (128-383) || cq GEMM (384-895) || kcv GEMM (896-1919) ===
__global__ __launch_bounds__(256) void gemm2gb_k(GJob P0, GJob P1, GJob Pw,
    const bf16* __restrict__ h, const float* __restrict__ w2, const float* __restrict__ b2,
    const float* __restrict__ dn, const float* __restrict__ ds, const float* __restrict__ rdb,
    bf16* __restrict__ qe, bf16* __restrict__ ke)
{
    __shared__ char smem[49152];
    int id = blockIdx.x;
    if (id < 128) gemm_body(Pw, id % Pw.gx, id / Pw.gx, smem);
    else if (id < 384) gb2x_body(id - 128, h, w2, b2, dn, ds, rdb, qe, ke, smem);
    else if (id < 896) {
        id -= 384;
        gemm_body(P0, id % P0.gx, id / P0.gx, smem);
    } else {
        id -= 896;
        gemm_body(P1, id % P1.gx, id / P1.gx, smem);
    }
}

// ============ XCD-aware block decomposition for attention (512 blocks) ============
__device__ __forceinline__ void attn_bid(int bid, int& bh, int& r0t) {
    const int xcd = bid & 7, s = bid >> 3;
    bh = (s >> 3) * 8 + xcd;
    r0t = s & 7;
}

// ============ MFMA flash self-attention (512 blocks) || spatial diffs (1024 blocks) ======
// relb stored as bf16: LDS 55808 -> 54528 B => 3 blocks/CU (was 2).
__global__ __launch_bounds__(512) void attnsd_k(
    const bf16* __restrict__ qb, const bf16* __restrict__ kb, const bf16* __restrict__ vtb,
    const float* __restrict__ relT, bf16* __restrict__ sab,
    const float* __restrict__ pp, bf16* __restrict__ sd)
{
    __shared__ bf16 Ks[2][64 * 64];
    __shared__ bf16 Vs[2][80 * 64];
    __shared__ bf16 Ps[128 * 64];
    __shared__ bf16 relb[2][320];
    const int t = threadIdx.x, w = t >> 6, lane = t & 63;
    if (blockIdx.x >= 512) {
        int g = (blockIdx.x - 512) * 512 + t;
        if (g < B_ * N_ * PP_) {
            const int c = g & 127;
            const int rown = g >> 7;
            const int n = rown & (N_ - 1);
            const int xx = n & 31, yy = (n >> 5) & 31;
            const float cur = pp[g];
            const float hd = (xx < 31) ? fabsf(pp[g + PP_] - cur) : 0.f;
            const float vd = (yy < 31) ? fabsf(pp[g + 32 * PP_] - cur) : 0.f;
            sd[(size_t)rown * 256 + c] = (bf16)hd;
            sd[(size_t)rown * 256 + 128 + c] = (bf16)vd;
        }
        return;
    }
    int bh, r0t;
    attn_bid(blockIdx.x, bh, r0t);
    const int b = bh >> 4, h = bh & 15, r0 = r0t * 128;
    const float* relTh = relT + h * 3969;
    const int y0 = r0 >> 5;

    {   // stage Q (128 rows x 128B) into Ps temp
        const bf16* g = qb + ((size_t)bh * 1024 + r0) * 64;
        #pragma unroll
        for (int r = 0; r < 2; ++r) {
            int i = r * 512 + t;
            int row = i >> 3, c = i & 7;
            const char* src = (const char*)g + (size_t)row * 128 + ((c ^ (row & 7)) << 4);
            gload16(src, Ps + (size_t)(r * 512 + (t & 448)) * 8);
        }
    }
    __syncthreads();
    bf16x8 aq[2];
    {
        const int qr = w * 16 + (lane & 15);
        aq[0] = lds8_swz(Ps, qr, (lane >> 4) * 16);
        aq[1] = lds8_swz(Ps, qr, 64 + (lane >> 4) * 16);
    }
    for (int i = t; i < 2048; i += 512) {
        int buf = i >> 10, idx = i & 1023;
        int row = 64 + (idx >> 6), col = idx & 63;
        Vs[buf][row * 64 + col] = (row == 64) ? (bf16)1.0f : (bf16)0.0f;
    }
    __syncthreads();
    stage64(kb + (size_t)bh * 65536, 128, Ks[0], t);
    stage64(vtb + (size_t)bh * 65536, 2048, Vs[0], t);
    if (t < 320) relb[0][t] = (bf16)(LOG2E * relTh[(y0 + 30 + (t >> 6)) * 63 + min(t & 63, 62)]);

    float m_run[4];
    f32x4 of[4], ofe;
    #pragma unroll
    for (int j = 0; j < 4; ++j) m_run[j] = -3e38f;
    #pragma unroll
    for (int dt = 0; dt < 4; ++dt) of[dt] = (f32x4){0.f, 0.f, 0.f, 0.f};
    ofe = (f32x4){0.f, 0.f, 0.f, 0.f};

    const int qrow_lo = (lane >> 4) * 4;
    int dybase[4];
    #pragma unroll
    for (int j = 0; j < 4; ++j) {
        int qg = r0 + w * 16 + qrow_lo + j;
        dybase[j] = (((qg >> 5) - y0) + 1) * 64 + (qg & 31) + 31;
    }
    __syncthreads();

    int cur = 0;
    for (int mt = 0; mt < 16; ++mt) {
        if (mt < 15) {
            stage64(kb + (size_t)bh * 65536 + (size_t)(mt + 1) * 64 * 64, 128, Ks[cur ^ 1], t);
            stage64(vtb + (size_t)bh * 65536 + (size_t)(mt + 1) * 64, 2048, Vs[cur ^ 1], t);
            if (t < 320)
                relb[cur ^ 1][t] = (bf16)(LOG2E * relTh[(y0 - 2 * (mt + 1) + 30 + (t >> 6)) * 63 + min(t & 63, 62)]);
        }
        f32x4 sf[4];
        __builtin_amdgcn_s_setprio(1);
        #pragma unroll
        for (int ct = 0; ct < 4; ++ct) {
            const int kr = ct * 16 + (lane & 15);
            f32x4 a = (f32x4){0.f, 0.f, 0.f, 0.f};
            a = MFMA_BF16(aq[0], lds8_swz(Ks[cur], kr, (lane >> 4) * 16), a);
            a = MFMA_BF16(aq[1], lds8_swz(Ks[cur], kr, 64 + (lane >> 4) * 16), a);
            sf[ct] = a;
        }
        __builtin_amdgcn_s_setprio(0);
        float p[4][4], lmax[4];
        #pragma unroll
        for (int j = 0; j < 4; ++j) lmax[j] = -3e38f;
        #pragma unroll
        for (int ct = 0; ct < 4; ++ct) {
            const int xm = (ct & 1) * 16 + (lane & 15);
            const int ro = (ct >> 1) * 64 + xm;
            #pragma unroll
            for (int j = 0; j < 4; ++j) {
                float s = sf[ct][j] + (float)relb[cur][dybase[j] - ro];
                p[ct][j] = s;
                lmax[j] = fmaxf(lmax[j], s);
            }
        }
        bool need = false;
        #pragma unroll
        for (int j = 0; j < 4; ++j) need |= (lmax[j] > m_run[j] + 8.0f);
        if (__any(need)) {
            float mx[4], alpha[4];
            #pragma unroll
            for (int j = 0; j < 4; ++j) mx[j] = lmax[j];
            #pragma unroll
            for (int d = 1; d < 16; d <<= 1)
                #pragma unroll
                for (int j = 0; j < 4; ++j) mx[j] = fmaxf(mx[j], __shfl_xor(mx[j], d));
            #pragma unroll
            for (int j = 0; j < 4; ++j) {
                float mn = fmaxf(m_run[j], mx[j]);
                alpha[j] = exp2f(m_run[j] - mn);
                m_run[j] = mn;
            }
            #pragma unroll
            for (int dt = 0; dt < 4; ++dt)
                #pragma unroll
                for (int j = 0; j < 4; ++j) of[dt][j] *= alpha[j];
            #pragma unroll
            for (int j = 0; j < 4; ++j) ofe[j] *= alpha[j];
        }
        #pragma unroll
        for (int ct = 0; ct < 4; ++ct)
            #pragma unroll
            for (int j = 0; j < 4; ++j)
                p[ct][j] = exp2f(p[ct][j] - m_run[j]);
        #pragma unroll
        for (int ct = 0; ct < 4; ++ct)
            #pragma unroll
            for (int j = 0; j < 4; ++j) {
                const int prow = w * 16 + qrow_lo + j;
                const int ch = (ct * 2 + ((lane & 15) >> 3)) ^ (prow & 7);
                *reinterpret_cast<bf16*>((char*)Ps + prow * 128 + (ch << 4) + (lane & 7) * 2)
                    = (bf16)p[ct][j];
            }
        asm volatile("s_waitcnt lgkmcnt(0)" ::: "memory");
        __builtin_amdgcn_sched_barrier(0);
        bf16x8 ap0 = lds8_swz(Ps, w * 16 + (lane & 15), (lane >> 4) * 16);
        bf16x8 ap1 = lds8_swz(Ps, w * 16 + (lane & 15), 64 + (lane >> 4) * 16);
        __builtin_amdgcn_s_setprio(1);
        #pragma unroll
        for (int dt = 0; dt < 4; ++dt) {
            const int vr = dt * 16 + (lane & 15);
            of[dt] = MFMA_BF16(ap0, lds8_swz(Vs[cur], vr, (lane >> 4) * 16), of[dt]);
            of[dt] = MFMA_BF16(ap1, lds8_swz(Vs[cur], vr, 64 + (lane >> 4) * 16), of[dt]);
        }
        {
            const int vr = 64 + (lane & 15);
            ofe = MFMA_BF16(ap0, lds8_swz(Vs[cur], vr, (lane >> 4) * 16), ofe);
            ofe = MFMA_BF16(ap1, lds8_swz(Vs[cur], vr, 64 + (lane >> 4) * 16), ofe);
        }
        __builtin_amdgcn_s_setprio(0);
        __syncthreads();
        cur ^= 1;
    }
    float inv[4];
    #pragma unroll
    for (int j = 0; j < 4; ++j) inv[j] = 1.f / __shfl(ofe[j], lane & 48);
    #pragma unroll
    for (int dt = 0; dt < 4; ++dt)
        #pragma unroll
        for (int j = 0; j < 4; ++j)
            sab[((size_t)(b * N_ + r0 + w * 16 + qrow_lo + j)) * C_ + h * 64 + dt * 16 + (lane & 15)] =
                (bf16)(of[dt][j] * inv[j]);
}

// ============ MFMA flash cross-attention, ext-K folded biases, lazy softmax ============
__global__ __launch_bounds__(512) void attn_cross_m(
    const bf16* __restrict__ cq, const bf16* __restrict__ qe,
    const bf16* __restrict__ ck, const bf16* __restrict__ ke,
    const bf16* __restrict__ cvt, bf16* __restrict__ cob)
{
    __shared__ bf16 Ks[2][64 * 64];
    __shared__ bf16 Ke[2][32 * 64];
    __shared__ bf16 Vs[2][80 * 64];
    __shared__ bf16 Ps[128 * 64];
    const int t = threadIdx.x, w = t >> 6, lane = t & 63;
    int bh, r0t;
    attn_bid(blockIdx.x, bh, r0t);
    const int b = bh >> 4, h = bh & 15, r0 = r0t * 128;

    {   // stage Q main (128 rows x 128B) into Ps temp
        const bf16* g = cq + ((size_t)bh * 1024 + r0) * 64;
        #pragma unroll
        for (int r = 0; r < 2; ++r) {
            int i = r * 512 + t;
            int row = i >> 3, c = i & 7;
            const char* src = (const char*)g + (size_t)row * 128 + ((c ^ (row & 7)) << 4);
            gload16(src, Ps + (size_t)(r * 512 + (t & 448)) * 8);
        }
    }
    stage64(qe + ((size_t)bh * 1024 + r0) * 32, 128, Ks[0], t);
    __syncthreads();
    bf16x8 aq[2], aqe;
    {
        const int qr = w * 16 + (lane & 15);
        aq[0] = lds8_swz(Ps, qr, (lane >> 4) * 16);
        aq[1] = lds8_swz(Ps, qr, 64 + (lane >> 4) * 16);
        aqe = lds8_ke(Ks[0], qr, lane >> 4);
    }
    for (int i = t; i < 2048; i += 512) {
        int buf = i >> 10, idx = i & 1023;
        int row = 64 + (idx >> 6), col = idx & 63;
        Vs[buf][row * 64 + col] = (row == 64) ? (bf16)1.0f : (bf16)0.0f;
    }
    __syncthreads();
    stage64(ck + (size_t)bh * 65536, 128, Ks[0], t);
    stage32(ke + (size_t)bh * 32768, Ke[0], t);
    stage64(cvt + (size_t)bh * 65536, 2048, Vs[0], t);

    float m_run[4];
    f32x4 of[4], ofe;
    #pragma unroll
    for (int j = 0; j < 4; ++j) m_run[j] = -3e38f;
    #pragma unroll
    for (int dt = 0; dt < 4; ++dt) of[dt] = (f32x4){0.f, 0.f, 0.f, 0.f};
    ofe = (f32x4){0.f, 0.f, 0.f, 0.f};
    const int qrow_lo = (lane >> 4) * 4;
    __syncthreads();

    int cur = 0;
    for (int mt = 0; mt < 16; ++mt) {
        if (mt < 15) {
            stage64(ck + (size_t)bh * 65536 + (size_t)(mt + 1) * 64 * 64, 128, Ks[cur ^ 1], t);
            stage32(ke + (size_t)bh * 32768 + (size_t)(mt + 1) * 64 * 32, Ke[cur ^ 1], t);
            stage64(cvt + (size_t)bh * 65536 + (size_t)(mt + 1) * 64, 2048, Vs[cur ^ 1], t);
        }
        f32x4 sf[4];
        __builtin_amdgcn_s_setprio(1);
        #pragma unroll
        for (int ct = 0; ct < 4; ++ct) {
            const int kr = ct * 16 + (lane & 15);
            f32x4 a = (f32x4){0.f, 0.f, 0.f, 0.f};
            a = MFMA_BF16(aq[0], lds8_swz(Ks[cur], kr, (lane >> 4) * 16), a);
            a = MFMA_BF16(aq[1], lds8_swz(Ks[cur], kr, 64 + (lane >> 4) * 16), a);
            a = MFMA_BF16(aqe, lds8_ke(Ke[cur], kr, lane >> 4), a);
            sf[ct] = a;
        }
        __builtin_amdgcn_s_setprio(0);
        float lmax[4];
        #pragma unroll
        for (int j = 0; j < 4; ++j)
            lmax[j] = fmaxf(fmaxf(sf[0][j], sf[1][j]), fmaxf(sf[2][j], sf[3][j]));
        bool need = false;
        #pragma unroll
        for (int j = 0; j < 4; ++j) need |= (lmax[j] > m_run[j] + 8.0f);
        if (__any(need)) {
            float mx[4], alpha[4];
            #pragma unroll
            for (int j = 0; j < 4; ++j) mx[j] = lmax[j];
            #pragma unroll
            for (int d = 1; d < 16; d <<= 1)
                #pragma unroll
                for (int j = 0; j < 4; ++j) mx[j] = fmaxf(mx[j], __shfl_xor(mx[j], d));
            #pragma unroll
            for (int j = 0; j < 4; ++j) {
                float mn = fmaxf(m_run[j], mx[j]);
                alpha[j] = exp2f(m_run[j] - mn);
                m_run[j] = mn;
            }
            #pragma unroll
            for (int dt = 0; dt < 4; ++dt)
                #pragma unroll
                for (int j = 0; j < 4; ++j) of[dt][j] *= alpha[j];
            #pragma unroll
            for (int j = 0; j < 4; ++j) ofe[j] *= alpha[j];
        }
        #pragma unroll
        for (int ct = 0; ct < 4; ++ct)
            #pragma unroll
            for (int j = 0; j < 4; ++j)
                sf[ct][j] = exp2f(sf[ct][j] - m_run[j]);
        #pragma unroll
        for (int ct = 0; ct < 4; ++ct)
            #pragma unroll
            for (int j = 0; j < 4; ++j) {
                const int prow = w * 16 + qrow_lo + j;
                const int ch = (ct * 2 + ((lane & 15) >> 3)) ^ (prow & 7);
                *reinterpret_cast<bf16*>((char*)Ps + prow * 128 + (ch << 4) + (lane & 7) * 2)
                    = (bf16)sf[ct][j];
            }
        asm volatile("s_waitcnt lgkmcnt(0)" ::: "memory");
        __builtin_amdgcn_sched_barrier(0);
        bf16x8 ap0 = lds8_swz(Ps, w * 16 + (lane & 15), (lane >> 4) * 16);
        bf16x8 ap1 = lds8_swz(Ps, w * 16 + (lane & 15), 64 + (lane >> 4) * 16);
        __builtin_amdgcn_s_setprio(1);
        #pragma unroll
        for (int dt = 0; dt < 4; ++dt) {
            const int vr = dt * 16 + (lane & 15);
            of[dt] = MFMA_BF16(ap0, lds8_swz(Vs[cur], vr, (lane >> 4) * 16), of[dt]);
            of[dt] = MFMA_BF16(ap1, lds8_swz(Vs[cur], vr, 64 + (lane >> 4) * 16), of[dt]);
        }
        {
            const int vr = 64 + (lane & 15);
            ofe = MFMA_BF16(ap0, lds8_swz(Vs[cur], vr, (lane >> 4) * 16), ofe);
            ofe = MFMA_BF16(ap1, lds8_swz(Vs[cur], vr, 64 + (lane >> 4) * 16), ofe);
        }
        __builtin_amdgcn_s_setprio(0);
        __syncthreads();
        cur ^= 1;
    }
    float inv[4];
    #pragma unroll
    for (int j = 0; j < 4; ++j) inv[j] = 1.f / __shfl(ofe[j], lane & 48);
    #pragma unroll
    for (int dt = 0; dt < 4; ++dt)
        #pragma unroll
        for (int j = 0; j < 4; ++j)
            cob[((size_t)(b * N_ + r0 + w * 16 + qrow_lo + j)) * C_ + h * 64 + dt * 16 + (lane & 15)] =
                (bf16)(of[dt][j] * inv[j]);
}

extern "C" void kernel_launch(void* const* d_in, const int* in_sizes, int n_in,
                              void* d_out, int out_size, void* d_ws, size_t ws_size,
                              hipStream_t stream)
{
    const float* x     = (const float*)d_in[0];
    const float* pl    = (const float*)d_in[1];
    const float* w_qkv = (const float*)d_in[2];
    const float* w_sp  = (const float*)d_in[3];
    const float* b_sp  = (const float*)d_in[4];
    const float* pl_w1 = (const float*)d_in[5];
    const float* pl_b1 = (const float*)d_in[6];
    const float* pl_w2 = (const float*)d_in[7];
    const float* pl_b2 = (const float*)d_in[8];
    const float* pl_w3 = (const float*)d_in[9];
    const float* pl_b3 = (const float*)d_in[10];
    const float* w_cq  = (const float*)d_in[11];
    const float* w_pk  = (const float*)d_in[12];
    const float* w_pv  = (const float*)d_in[13];
    const float* w_cp  = (const float*)d_in[14];
    const float* b_cp  = (const float*)d_in[15];
    const float* rdb   = (const float*)d_in[16];
    const float* ds_w1 = (const float*)d_in[17];
    const float* ds_b1 = (const float*)d_in[18];
    const float* ds_w2 = (const float*)d_in[19];
    const float* ds_b2 = (const float*)d_in[20];
    const float* gb_w1 = (const float*)d_in[21];
    const float* gb_b1 = (const float*)d_in[22];
    const float* gb_w2 = (const float*)d_in[23];
    const float* gb_b2 = (const float*)d_in[24];
    const float* rel_t = (const float*)d_in[25];
    const float* gfw1  = (const float*)d_in[26];
    const float* gfb1  = (const float*)d_in[27];
    const float* gfw2  = (const float*)d_in[28];
    const float* gfb2  = (const float*)d_in[29];

    char* W = (char*)d_ws;
    float* out = (float*)d_out;
    const size_t MB = 1ull << 20;
    const size_t KB = 1024;

    bf16* qb     = (bf16*)(W + 0);           // 8MB ; cqb reuses
    bf16* kb     = (bf16*)(W + 8 * MB);      // 8MB ; ckb reuses
    bf16* vtb    = (bf16*)(W + 16 * MB);     // 8MB ; cvtb reuses
    bf16* cqb    = qb;
    bf16* ckb    = kb;
    bf16* cvtb   = vtb;
    bf16* xb     = (bf16*)(W + 24 * MB);     // 8MB
    bf16* wqkvT  = (bf16*)(W + 32 * MB);     // 6MB
    bf16* wspB   = (bf16*)(W + 38 * MB);     // 2MB (plain cast of w_sp)
    bf16* wcqT   = (bf16*)(W + 40 * MB);     // 2MB
    bf16* wpkT   = (bf16*)(W + 42 * MB);               // 256KB
    bf16* wpvT   = (bf16*)(W + 42 * MB + 256 * KB);    // 256KB (contiguous after wpkT)
    bf16* wcpB   = (bf16*)(W + 43 * MB);     // 2MB (plain cast of w_cp)
    bf16* gf1tT  = (bf16*)(W + 45 * MB);     // 2MB (gfw1 top 1024 rows, transposed)
    bf16* gf1bT  = (bf16*)(W + 47 * MB);     // 256KB (gfw1 bottom 128 rows, transposed)
    bf16* gfw2T  = (bf16*)(W + 48 * MB);     // 2MB
    bf16* gbw1T  = (bf16*)(W + 50 * MB);               // 256KB
    bf16* plw2T  = (bf16*)(W + 50 * MB + 256 * KB);    // 64KB
    bf16* plw3T  = (bf16*)(W + 50 * MB + 320 * KB);    // 32KB
    bf16* sab    = (bf16*)(W + 51 * MB);     // 8MB ; cob reuses
    bf16* cob    = sab;
    float* pp    = (float*)(W + 67 * MB);    // 2MB
    bf16* ppb    = (bf16*)(W + 69 * MB);     // 1MB
    bf16* sdb16  = (bf16*)(W + 70 * MB);     // 2MB
    bf16* h1b    = (bf16*)(W + 72 * MB);     // 2MB
    bf16* gbh    = (bf16*)(W + 75 * MB);     // 4MB
    float* dsb   = (float*)(W + 79 * MB);              // 256KB
    float* dnb   = (float*)(W + 79 * MB + 256 * KB);   // 64KB
    float2* rtab = (float2*)(W + 80 * MB);             // 256KB
    float* relTb = (float*)(W + 80 * MB + 256 * KB);   // 254KB
    bf16* hidb   = (bf16*)(W + 81 * MB);     // 8MB
    bf16* qeb    = (bf16*)(W + 89 * MB);     // 4MB [64][1024][32]
    bf16* keb    = (bf16*)(W + 93 * MB);     // 4MB
    bf16* wcgT   = (bf16*)(W + 97 * MB);     // 2MB (combined (w_cp@gfw1_top)^T)
    float* bscgb = (float*)(W + 99 * MB);              // 4KB
    float* bscb  = (float*)(W + 99 * MB + 8 * KB);     // 4KB
    bf16* wscT   = (bf16*)(W + 100 * MB);    // 2MB (combined (w_sp@w_cq)^T) -> 102MB total

    const dim3 blk(256);

    TJobs J;
    J.src[0] = w_qkv;              J.dst[0] = wqkvT; J.K[0] = 1024; J.N[0] = 3072;
    J.src[1] = w_cq;               J.dst[1] = wcqT;  J.K[1] = 1024; J.N[1] = 1024;
    J.src[2] = w_pk;               J.dst[2] = wpkT;  J.K[2] = 128;  J.N[2] = 1024;
    J.src[3] = w_pv;               J.dst[3] = wpvT;  J.K[3] = 128;  J.N[3] = 1024;
    J.src[4] = gfw1;               J.dst[4] = gf1tT; J.K[4] = 1024; J.N[4] = 1024;
    J.src[5] = gfw1 + 1024 * 1024; J.dst[5] = gf1bT; J.K[5] = 128;  J.N[5] = 1024;
    J.src[6] = gfw2;               J.dst[6] = gfw2T; J.K[6] = 1024; J.N[6] = 1024;
    J.src[7] = gb_w1;              J.dst[7] = gbw1T; J.K[7] = 256;  J.N[7] = 512;
    J.src[8] = pl_w2;              J.dst[8] = plw2T; J.K[8] = 256;  J.N[8] = 128;
    J.src[9] = pl_w3;              J.dst[9] = plw3T; J.K[9] = 128;  J.N[9] = 128;
    {
        int acc = 0;
        for (int j = 0; j < 10; ++j) {
            J.base[j] = acc;
            acc += (J.N[j] >> 5) * (J.K[j] >> 5);
        }
        J.base[10] = acc;
    }
    const int pre_blocks = J.base[10] + 4096 + 512 + 377 + 32 + 1024;

    auto mkjob = [](const bf16* A, const bf16* A2, const bf16* Bt, const bf16* Bt2,
                    const float* bias, const float* resid,
                    void* o0, void* o1, void* o2, const float2* rt,
                    int N, int K, int K1A, int K1B, int epi, int ag, int gx, float sc) {
        GJob g;
        g.A = A; g.A2 = A2; g.Bt = Bt; g.Bt2 = Bt2; g.bias = bias; g.resid = resid;
        g.out0 = o0; g.out1 = o1; g.out2 = o2; g.rtab = rt;
        g.N = N; g.K = K; g.K1A = K1A; g.K1B = K1B; g.epi = epi; g.act_gelu = ag;
        g.gx = gx; g.scale = sc;
        return g;
    };

    // 1. merged preamble (+ w_cp/w_sp casts + bscg/bsc GEMVs)
    pre_k<<<pre_blocks, blk, 0, stream>>>(J, x, xb, w_cp, wcpB, w_sp, wspB,
        rel_t, relTb, rtab, b_cp, gfw1, gfb1, bscgb, b_sp, w_cq, bscb,
        pl, pl_w1, pl_b1, ds_w1, ds_b1, ds_w2, ds_b2, h1b, dsb, dnb);
    // 2. wsc combine || pl23m || qkv GEMM
    GJob jqkv = mkjob(xb, nullptr, wqkvT, nullptr, nullptr, nullptr,
                      qb, kb, vtb, rtab, 3072, 1024, 1024, 1024, 2, 0, 48, 0.125f * LOG2E);
    GJob jwsc = mkjob(wcqT, nullptr, wspB, nullptr, nullptr, nullptr,
                      wscT, nullptr, nullptr, nullptr, 1024, 1024, 1024, 1024, 1, 0, 16, 1.f);
    qkvpl_k<<<128 + 64 + 1536, blk, 0, stream>>>(jqkv, jwsc,
        h1b, plw2T, pl_b2, plw3T, pl_b3, pp, ppb);
    // 3. self attention || spatial diffs
    attnsd_k<<<512 + 1024, dim3(512), 0, stream>>>(qb, kb, vtb, relTb, sab, pp, sdb16);
    // 4. gb layer1 (gelu)
    GJob jgb1 = mkjob(sdb16, nullptr, gbw1T, nullptr, gb_b1, nullptr,
                      gbh, nullptr, nullptr, nullptr, 512, 256, 256, 256, 1, 1, 8, 1.f);
    gemm_k<<<256, blk, 0, stream>>>(jgb1);
    // 5. quad launch: wcg combine || gb2x || cq = rope(sa@wsc + bsc)*(dsr) || ck+cv split
    GJob jcq  = mkjob(sab, nullptr, wscT, nullptr, bscb, dsb,
                      cqb, nullptr, nullptr, rtab, 1024, 1024, 1024, 1024, 6, 0, 16, 0.125f * LOG2E);
    GJob jkcv = mkjob(ppb, nullptr, wpkT, nullptr, nullptr, nullptr,
                      ckb, nullptr, cvtb, rtab, 2048, 128, 128, 128, 7, 0, 32, 1.f);
    GJob jwcg = mkjob(gf1tT, nullptr, wcpB, nullptr, nullptr, nullptr,
                      wcgT, nullptr, nullptr, nullptr, 1024, 1024, 1024, 1024, 1, 0, 16, 1.f);
    gemm2gb_k<<<128 + 256 + 512 + 1024, blk, 0, stream>>>(jcq, jkcv, jwcg,
        gbh, gb_w2, gb_b2, dnb, dsb, rdb, qeb, keb);
    // 6. cross attention
    attn_cross_m<<<512, dim3(512), 0, stream>>>(cqb, qeb, ckb, keb, cvtb, cob);
    // 7. gfe1 with folded cross-proj: gelu(cob@wcgT^T + pp@gf1bT^T + bscg)
    GJob jg1 = mkjob(cob, ppb, wcgT, gf1bT, bscgb, nullptr,
                     hidb, nullptr, nullptr, nullptr, 1024, 1152, 1024, 1024, 1, 1, 16, 1.f);
    gemm_k<<<512, blk, 0, stream>>>(jg1);
    // 8. gfe2 + bias + residual -> fp32 out
    GJob jg2 = mkjob(hidb, nullptr, gfw2T, nullptr, gfb2, x,
                     out, nullptr, nullptr, nullptr, 1024, 1024, 1024, 1024, 0, 0, 16, 1.f);
    gemm_k<<<512, blk, 0, stream>>>(jg2);
}

// Round 26
// 281.968 us; speedup vs baseline: 1.0502x; 1.0502x over previous
//
#include <hip/hip_runtime.h>
#include <math.h>

#define B_ 4
#define N_ 1024
#define C_ 1024
#define NH_ 16
#define HD_ 64
#define PP_ 128
#define LOG2E 1.4426950408889634f

typedef __bf16 bf16;
typedef __attribute__((ext_vector_type(8))) __bf16 bf16x8;
typedef __attribute__((ext_vector_type(4))) __bf16 bf16x4;
typedef __attribute__((ext_vector_type(4))) float f32x4;

#define MFMA_BF16(a, b, c) __builtin_amdgcn_mfma_f32_16x16x32_bf16((a), (b), (c), 0, 0, 0)

__device__ __forceinline__ float gelu_f(float x) {
    return 0.5f * x * (1.0f + erff(x * 0.70710678118654752f));
}

__device__ __forceinline__ void gload16(const void* g, void* l) {
    __builtin_amdgcn_global_load_lds(
        (const __attribute__((address_space(1))) void*)g,
        (__attribute__((address_space(3))) void*)l, 16, 0, 0);
}

// stage a 64-row x 128B tile into LDS, XOR-swizzled source, 512 threads (1 chunk each)
__device__ __forceinline__ void stage64(const bf16* __restrict__ g, int pitchB,
                                        bf16* lds, int t) {
    int row = t >> 3, c = t & 7;
    const char* src = (const char*)g + (size_t)row * pitchB + ((c ^ (row & 7)) << 4);
    gload16(src, lds + (size_t)(t & 448) * 8);
}

// stage a 32-row x 128B tile (ext: 64 k-rows x 64B packed 2-per-LDS-row), 256 of 512 threads
__device__ __forceinline__ void stage32(const bf16* __restrict__ g, bf16* lds, int t) {
    if (t < 256) {
        int row = t >> 3, c = t & 7;
        const char* src = (const char*)g + (size_t)row * 128 + ((c ^ (row & 7)) << 4);
        gload16(src, lds + (size_t)(t & 192) * 8);
    }
}

__device__ __forceinline__ bf16x8 lds8_swz(const bf16* lds, int row, int colb) {
    return *reinterpret_cast<const bf16x8*>(
        (const char*)lds + row * 128 + (colb ^ ((row & 7) << 4)));
}

// 256B-row variant (for pl23m tiles)
__device__ __forceinline__ bf16x8 lds8_swz256(const bf16* lds, int row, int colb) {
    return *reinterpret_cast<const bf16x8*>(
        (const char*)lds + row * 256 + (colb ^ ((row & 7) << 4)));
}

// read 16B of ext row kr (64B rows packed 2-per-LDS-row), chunk g in 0..3
__device__ __forceinline__ bf16x8 lds8_ke(const bf16* lds, int kr, int g) {
    int r = kr >> 1;
    int ch = ((kr & 1) * 4 + g) ^ (r & 7);
    return *reinterpret_cast<const bf16x8*>((const char*)lds + r * 128 + (ch << 4));
}

// ============ transpose-cast job table (10 jobs) ============
struct TJobs {
    const float* src[11];
    bf16* dst[11];
    int K[11];
    int N[11];
    int base[12];   // prefix tile offsets; base[10] = total tiles
};

// ===== merged preamble: tcast | cast x | cast w_cp | cast w_sp | tables | bscg | bsc | pl1
__global__ __launch_bounds__(256) void pre_k(
    TJobs J, const float* __restrict__ x, bf16* __restrict__ xb,
    const float* __restrict__ w_cp, bf16* __restrict__ wcpB,
    const float* __restrict__ w_sp, bf16* __restrict__ wspB,
    const float* __restrict__ rel_table, float* __restrict__ relT, float2* __restrict__ rt,
    const float* __restrict__ b_cp, const float* __restrict__ gfw1,
    const float* __restrict__ gfb1, float* __restrict__ bscg,
    const float* __restrict__ b_sp, const float* __restrict__ w_cq, float* __restrict__ bsc,
    const float* __restrict__ pl,
    const float* __restrict__ w1, const float* __restrict__ b1,
    const float* __restrict__ dw1, const float* __restrict__ db1,
    const float* __restrict__ dw2, const float* __restrict__ db2,
    bf16* __restrict__ h1b, float* __restrict__ ds, float* __restrict__ dn)
{
    __shared__ float tl[32][33];
    __shared__ float plr[6];
    __shared__ float dh[64];
    __shared__ float red[4][64];
    const int t = threadIdx.x;
    const int bid = blockIdx.x;
    const int ntc = J.base[10];
    if (bid < ntc) {
        int tile = bid;
        int j = 0;
        while (j + 1 < 10 && tile >= J.base[j + 1]) ++j;
        tile -= J.base[j];
        const int Kd = J.K[j], Nd = J.N[j];
        const int ntx = Nd >> 5;
        const int n0 = (tile % ntx) * 32, k0 = (tile / ntx) * 32;
        const int tx = t & 31, ty = t >> 5;
        const float* src = J.src[j];
        bf16* dst = J.dst[j];
        #pragma unroll
        for (int r = 0; r < 4; ++r) {
            int kk = ty + r * 8;
            tl[kk][tx] = src[(size_t)(k0 + kk) * Nd + n0 + tx];
        }
        __syncthreads();
        #pragma unroll
        for (int r = 0; r < 4; ++r) {
            int nn = ty + r * 8;
            dst[(size_t)(n0 + nn) * Kd + k0 + tx] = (bf16)tl[tx][nn];
        }
    } else if (bid < ntc + 4096) {
        int g = (bid - ntc) * 256 + t;
        float4 v = reinterpret_cast<const float4*>(x)[g];
        bf16x4 o = {(bf16)v.x, (bf16)v.y, (bf16)v.z, (bf16)v.w};
        reinterpret_cast<bf16x4*>(xb)[g] = o;
    } else if (bid < ntc + 4096 + 256) {
        int g = (bid - ntc - 4096) * 256 + t;
        float4 v = reinterpret_cast<const float4*>(w_cp)[g];
        bf16x4 o = {(bf16)v.x, (bf16)v.y, (bf16)v.z, (bf16)v.w};
        reinterpret_cast<bf16x4*>(wcpB)[g] = o;
    } else if (bid < ntc + 4096 + 512) {
        int g = (bid - ntc - 4096 - 256) * 256 + t;
        float4 v = reinterpret_cast<const float4*>(w_sp)[g];
        bf16x4 o = {(bf16)v.x, (bf16)v.y, (bf16)v.z, (bf16)v.w};
        reinterpret_cast<bf16x4*>(wspB)[g] = o;
    } else if (bid < ntc + 4096 + 512 + 377) {
        int g = (bid - ntc - 4096 - 512) * 256 + t;
        if (g < 32768) {
            const int n = g >> 5, i = g & 31;
            const float inv = powf(10000.0f, -(float)(2 * i) / 64.0f);
            const float ang = (float)n * inv;
            rt[g] = make_float2(cosf(ang), sinf(ang));
        } else {
            int i = g - 32768;
            if (i < 16 * 3969) {
                int h = i / 3969, idx = i - h * 3969;
                relT[i] = rel_table[idx * 16 + h];
            }
        }
    } else if (bid < ntc + 4096 + 512 + 377 + 16) {
        // bscg[c] = gfb1[c] + sum_{j<1024} b_cp[j] * gfw1[j][c]
        const int pb = bid - ntc - 4096 - 512 - 377;
        const int c = pb * 64 + (t & 63);
        const int js = t >> 6;
        float a = 0.f;
        #pragma unroll 8
        for (int j = js * 256; j < js * 256 + 256; ++j)
            a = fmaf(b_cp[j], gfw1[(size_t)j * 1024 + c], a);
        red[js][t & 63] = a;
        __syncthreads();
        if (t < 64) {
            int cc = pb * 64 + t;
            bscg[cc] = red[0][t] + red[1][t] + red[2][t] + red[3][t] + gfb1[cc];
        }
    } else if (bid < ntc + 4096 + 512 + 377 + 32) {
        // bsc[c] = sum_{j<1024} b_sp[j] * w_cq[j][c]
        const int pb = bid - ntc - 4096 - 512 - 377 - 16;
        const int c = pb * 64 + (t & 63);
        const int js = t >> 6;
        float a = 0.f;
        #pragma unroll 8
        for (int j = js * 256; j < js * 256 + 256; ++j)
            a = fmaf(b_sp[j], w_cq[(size_t)j * 1024 + c], a);
        red[js][t & 63] = a;
        __syncthreads();
        if (t < 64) {
            int cc = pb * 64 + t;
            bsc[cc] = red[0][t] + red[1][t] + red[2][t] + red[3][t];
        }
    } else {
        const int pb = bid - ntc - 4096 - 512 - 377 - 32;
        #pragma unroll 1
        for (int rr = 0; rr < 4; ++rr) {
            const int row = pb * 4 + rr;
            if (t < 6) plr[t] = pl[(size_t)row * 6 + t];
            __syncthreads();
            {
                float a = b1[t];
                #pragma unroll
                for (int j = 0; j < 6; ++j) a = fmaf(plr[j], w1[j * 256 + t], a);
                h1b[(size_t)row * 256 + t] = (bf16)gelu_f(a);
            }
            if (t < 64) {
                float d = db1[t];
                #pragma unroll
                for (int j = 0; j < 6; ++j) d = fmaf(plr[j], dw1[j * 64 + t], d);
                dh[t] = gelu_f(d);
            }
            if (t == 0) {
                float xx = plr[0], yy = plr[1], zz = plr[2];
                float nrm = fmaxf(sqrtf(xx * xx + yy * yy + zz * zz), 1e-12f);
                dn[(size_t)row * 4 + 0] = xx / nrm;
                dn[(size_t)row * 4 + 1] = yy / nrm;
                dn[(size_t)row * 4 + 2] = zz / nrm;
                dn[(size_t)row * 4 + 3] = 0.f;
            }
            __syncthreads();
            if (t < 16) {
                float d = db2[t];
                #pragma unroll 8
                for (int j = 0; j < 64; ++j) d = fmaf(dh[j], dw2[j * 16 + t], d);
                ds[(size_t)row * 16 + t] = tanhf(d);
            }
            __syncthreads();
        }
    }
}

// ============ GEMM job descriptor ============
struct GJob {
    const bf16* A; const bf16* A2; const bf16* Bt; const bf16* Bt2;
    const float* bias; const float* resid;
    void* out0; void* out1; void* out2;
    const float2* rtab;
    int N, K, K1A, K1B, epi, act_gelu, gx;
    float scale;
};

// ============ MFMA GEMM body, 128x64 tile, BK=64, 2-phase double-buffered ============
__device__ __forceinline__ void gemm_body(const GJob& P, int bx, int by, char* smem)
{
    const bf16* A = P.A; const bf16* A2 = P.A2;
    const bf16* Bt = P.Bt; const bf16* Bt2 = P.Bt2;
    const float* bias = P.bias; const float* resid = P.resid;
    void* out0 = P.out0; void* out1 = P.out1; void* out2 = P.out2;
    const float2* rtab = P.rtab;
    const int N = P.N, K = P.K, K1A = P.K1A, K1B = P.K1B;
    const int epi = P.epi, act_gelu = P.act_gelu;
    const float scale = P.scale;

    bf16 (*As)[128 * 64] = (bf16(*)[128 * 64])smem;
    bf16 (*Bs)[64 * 64]  = (bf16(*)[64 * 64])(smem + 32768);
    const int t = threadIdx.x;
    const int w = t >> 6, lane = t & 63;
    const int row0 = by * 128, col0 = bx * 64;
    const int wm = w >> 1, wn = w & 1;
    const int K2A = K - K1A, K2B = K - K1B;
    f32x4 acc[4][2];
    #pragma unroll
    for (int mi = 0; mi < 4; ++mi)
        #pragma unroll
        for (int ni = 0; ni < 2; ++ni)
            acc[mi][ni] = (f32x4){0.f, 0.f, 0.f, 0.f};

    #define STAGE_AB64(k0, buf)                                                \
        {                                                                      \
            const bf16* abase; int apitch;                                     \
            if ((k0) < K1A) { abase = A + (k0); apitch = K1A; }                \
            else            { abase = A2 + ((k0) - K1A); apitch = K2A; }       \
            _Pragma("unroll")                                                  \
            for (int r = 0; r < 4; ++r) {                                      \
                int c = r * 256 + t;                                           \
                int rr = c >> 3, cc = c & 7;                                   \
                const char* srca = (const char*)(abase + (size_t)(row0 + rr) * apitch) \
                                   + ((cc ^ (rr & 7)) << 4);                   \
                gload16(srca, As[buf] + (size_t)(r * 256 + (t & 192)) * 8);    \
            }                                                                  \
            const bf16* bbase; int bpitch;                                     \
            if ((k0) < K1B) { bbase = Bt + (k0); bpitch = K1B; }               \
            else            { bbase = Bt2 + ((k0) - K1B); bpitch = K2B; }      \
            _Pragma("unroll")                                                  \
            for (int r = 0; r < 2; ++r) {                                      \
                int c = r * 256 + t;                                           \
                int rr = c >> 3, cc = c & 7;                                   \
                const char* srcb = (const char*)(bbase + (size_t)(col0 + rr) * bpitch) \
                                   + ((cc ^ (rr & 7)) << 4);                   \
                gload16(srcb, Bs[buf] + (size_t)(r * 256 + (t & 192)) * 8);    \
            }                                                                  \
        }

    int cur = 0;
    const int nk = K >> 6;
    STAGE_AB64(0, 0);
    __syncthreads();
    for (int kk = 0; kk < nk; ++kk) {
        if (kk + 1 < nk) STAGE_AB64((kk + 1) * 64, cur ^ 1);
        bf16x8 af[4][2], bfv[2][2];
        #pragma unroll
        for (int mi = 0; mi < 4; ++mi)
            #pragma unroll
            for (int kh = 0; kh < 2; ++kh)
                af[mi][kh] = lds8_swz(As[cur], wm * 64 + mi * 16 + (lane & 15),
                                      kh * 64 + (lane >> 4) * 16);
        #pragma unroll
        for (int ni = 0; ni < 2; ++ni)
            #pragma unroll
            for (int kh = 0; kh < 2; ++kh)
                bfv[ni][kh] = lds8_swz(Bs[cur], wn * 32 + ni * 16 + (lane & 15),
                                       kh * 64 + (lane >> 4) * 16);
        #pragma unroll
        for (int kh = 0; kh < 2; ++kh)
            #pragma unroll
            for (int mi = 0; mi < 4; ++mi)
                #pragma unroll
                for (int ni = 0; ni < 2; ++ni)
                    acc[mi][ni] = MFMA_BF16(af[mi][kh], bfv[ni][kh], acc[mi][ni]);
        __syncthreads();
        cur ^= 1;
    }
    #undef STAGE_AB64

    #pragma unroll
    for (int mi = 0; mi < 4; ++mi) {
        #pragma unroll
        for (int ni = 0; ni < 2; ++ni) {
            const int col = col0 + wn * 32 + ni * 16 + (lane & 15);
            if (epi <= 1 || epi == 5) {
                const float bv = bias ? bias[col] : 0.f;
                #pragma unroll
                for (int j = 0; j < 4; ++j) {
                    const int row = row0 + wm * 64 + mi * 16 + (lane >> 4) * 4 + j;
                    float v = acc[mi][ni][j] + bv;
                    if (act_gelu) v = gelu_f(v);
                    if (epi == 0) {
                        if (resid) v += resid[(size_t)row * N + col];
                        ((float*)out0)[(size_t)row * N + col] = v;
                    } else if (epi == 1) {
                        ((bf16*)out0)[(size_t)row * N + col] = (bf16)v;
                    } else {
                        ((float*)out0)[(size_t)row * N + col] = v;
                        ((bf16*)out1)[(size_t)row * N + col] = (bf16)v;
                    }
                }
            } else if (epi == 2) {
                const int reg = col >> 10;         // 0=q 1=k 2=v
                const int h = (col >> 6) & 15, d = col & 63;
                if (reg <= 1) {
                    bf16* dst = reg == 0 ? (bf16*)out0 : (bf16*)out1;
                    const float sc = reg == 0 ? scale : 1.0f;
                    #pragma unroll
                    for (int j = 0; j < 4; ++j) {
                        const int row = row0 + wm * 64 + mi * 16 + (lane >> 4) * 4 + j;
                        const int b = row >> 10, n = row & 1023;
                        float v = acc[mi][ni][j];
                        float pv = __shfl_xor(v, 1);
                        float2 cs = rtab[(n << 5) + (d >> 1)];
                        float o = (d & 1) == 0 ? v * cs.x - pv * cs.y
                                               : v * cs.x + pv * cs.y;
                        dst[((size_t)((b * 16 + h) * 1024 + n)) * 64 + d] = (bf16)(o * sc);
                    }
                } else {
                    bf16x4 o4;
                    #pragma unroll
                    for (int j = 0; j < 4; ++j) o4[j] = (bf16)acc[mi][ni][j];
                    const int row = row0 + wm * 64 + mi * 16 + (lane >> 4) * 4;
                    const int b = row >> 10, n = row & 1023;
                    *reinterpret_cast<bf16x4*>(
                        (bf16*)out2 + ((size_t)((b * 16 + h) * 64 + d)) * 1024 + n) = o4;
                }
            } else if (epi == 3 || epi == 6) {
                const int h = (col >> 6) & 15, d = col & 63;
                const float bv = bias ? bias[col] : 0.f;
                #pragma unroll
                for (int j = 0; j < 4; ++j) {
                    const int row = row0 + wm * 64 + mi * 16 + (lane >> 4) * 4 + j;
                    const int b = row >> 10, n = row & 1023;
                    float v = acc[mi][ni][j] + bv;
                    float pv = __shfl_xor(v, 1);
                    float2 cs = rtab[(n << 5) + (d >> 1)];
                    float o = (d & 1) == 0 ? v * cs.x - pv * cs.y
                                           : v * cs.x + pv * cs.y;
                    float sc = scale;
                    if (epi == 6) sc *= 1.0f + resid[(size_t)row * 16 + h];
                    ((bf16*)out0)[((size_t)((b * 16 + h) * 1024 + n)) * 64 + d] = (bf16)(o * sc);
                }
            } else if (epi == 7) {
                const int reg = col >> 10;         // 0=ck(rope) 1=cv(transposed)
                const int h = (col >> 6) & 15, d = col & 63;
                if (reg == 0) {
                    #pragma unroll
                    for (int j = 0; j < 4; ++j) {
                        const int row = row0 + wm * 64 + mi * 16 + (lane >> 4) * 4 + j;
                        const int b = row >> 10, n = row & 1023;
                        float v = acc[mi][ni][j];
                        float pv = __shfl_xor(v, 1);
                        float2 cs = rtab[(n << 5) + (d >> 1)];
                        float o = (d & 1) == 0 ? v * cs.x - pv * cs.y
                                               : v * cs.x + pv * cs.y;
                        ((bf16*)out0)[((size_t)((b * 16 + h) * 1024 + n)) * 64 + d] = (bf16)o;
                    }
                } else {
                    bf16x4 o4;
                    #pragma unroll
                    for (int j = 0; j < 4; ++j) o4[j] = (bf16)acc[mi][ni][j];
                    const int row = row0 + wm * 64 + mi * 16 + (lane >> 4) * 4;
                    const int b = row >> 10, n = row & 1023;
                    *reinterpret_cast<bf16x4*>(
                        (bf16*)out2 + ((size_t)((b * 16 + h) * 64 + d)) * 1024 + n) = o4;
                }
            } else {  // epi == 4: transposed head-major
                const int h = (col >> 6) & 15, d = col & 63;
                bf16x4 o4;
                #pragma unroll
                for (int j = 0; j < 4; ++j) o4[j] = (bf16)acc[mi][ni][j];
                const int row = row0 + wm * 64 + mi * 16 + (lane >> 4) * 4;
                const int b = row >> 10, n = row & 1023;
                *reinterpret_cast<bf16x4*>(
                    (bf16*)out0 + ((size_t)((b * 16 + h) * 64 + d)) * 1024 + n) = o4;
            }
        }
    }
}

// ============ plucker layers 2+3 body (uses 48KB smem) ============
__device__ __forceinline__ void pl23m_body(
    int bid, const bf16* __restrict__ h1, const bf16* __restrict__ w2T,
    const float* __restrict__ b2, const bf16* __restrict__ w3T, const float* __restrict__ b3,
    float* __restrict__ pp, bf16* __restrict__ ppb, char* smem)
{
    bf16* Am = (bf16*)smem;              // 16KB
    bf16* Wm = (bf16*)(smem + 16384);    // 32KB
    const int t = threadIdx.x, w = t >> 6, lane = t & 63;
    const int row0 = bid * 64;
    f32x4 acc[8];
    #pragma unroll
    for (int nt = 0; nt < 8; ++nt) acc[nt] = (f32x4){0.f, 0.f, 0.f, 0.f};

    for (int kc = 0; kc < 2; ++kc) {
        #pragma unroll
        for (int r = 0; r < 4; ++r) {
            int i = r * 256 + t;
            int row = i >> 4, c = i & 15;
            const char* src = (const char*)(h1 + (size_t)(row0 + row) * 256 + kc * 128)
                              + ((c ^ (row & 7)) << 4);
            gload16(src, Am + (size_t)(r * 256 + (t & 192)) * 8);
        }
        #pragma unroll
        for (int r = 0; r < 8; ++r) {
            int i = r * 256 + t;
            int row = i >> 4, c = i & 15;
            const char* src = (const char*)(w2T + (size_t)row * 256 + kc * 128)
                              + ((c ^ (row & 7)) << 4);
            gload16(src, Wm + (size_t)(r * 256 + (t & 192)) * 8);
        }
        __syncthreads();
        #pragma unroll
        for (int step = 0; step < 4; ++step) {
            bf16x8 af = lds8_swz256(Am, w * 16 + (lane & 15), step * 64 + (lane >> 4) * 16);
            #pragma unroll
            for (int nt = 0; nt < 8; ++nt) {
                bf16x8 bfv = lds8_swz256(Wm, nt * 16 + (lane & 15), step * 64 + (lane >> 4) * 16);
                acc[nt] = MFMA_BF16(af, bfv, acc[nt]);
            }
        }
        __syncthreads();
    }
    #pragma unroll
    for (int r = 0; r < 8; ++r) {
        int i = r * 256 + t;
        int row = i >> 4, c = i & 15;
        const char* src = (const char*)(w3T + (size_t)row * 128) + ((c ^ (row & 7)) << 4);
        gload16(src, Wm + (size_t)(r * 256 + (t & 192)) * 8);
    }
    #pragma unroll
    for (int nt = 0; nt < 8; ++nt) {
        const int col = nt * 16 + (lane & 15);
        const float bv = b2[col];
        #pragma unroll
        for (int j = 0; j < 4; ++j) {
            const int row = w * 16 + (lane >> 4) * 4 + j;
            const int byte = row * 256 + (((col * 2) & ~15) ^ ((row & 7) << 4)) + ((col * 2) & 15);
            *reinterpret_cast<bf16*>((char*)Am + byte) = (bf16)gelu_f(acc[nt][j] + bv);
        }
    }
    __syncthreads();
    f32x4 acc2[8];
    #pragma unroll
    for (int nt = 0; nt < 8; ++nt) acc2[nt] = (f32x4){0.f, 0.f, 0.f, 0.f};
    #pragma unroll
    for (int step = 0; step < 4; ++step) {
        bf16x8 af = lds8_swz256(Am, w * 16 + (lane & 15), step * 64 + (lane >> 4) * 16);
        #pragma unroll
        for (int nt = 0; nt < 8; ++nt) {
            bf16x8 bfv = lds8_swz256(Wm, nt * 16 + (lane & 15), step * 64 + (lane >> 4) * 16);
            acc2[nt] = MFMA_BF16(af, bfv, acc2[nt]);
        }
    }
    #pragma unroll
    for (int nt = 0; nt < 8; ++nt) {
        const int col = nt * 16 + (lane & 15);
        const float bv = b3[col];
        #pragma unroll
        for (int j = 0; j < 4; ++j) {
            const int row = row0 + w * 16 + (lane >> 4) * 4 + j;
            const float v = acc2[nt][j] + bv;
            pp[(size_t)row * 128 + col] = v;
            ppb[(size_t)row * 128 + col] = (bf16)v;
        }
    }
}

// ============ gb layer2 body (uses 32KB of smem) ============
__device__ __forceinline__ void gb2x_body(
    int bid, const bf16* __restrict__ h, const float* __restrict__ w2,
    const float* __restrict__ b2, const float* __restrict__ dn,
    const float* __restrict__ ds, const float* __restrict__ rdb,
    bf16* __restrict__ qe, bf16* __restrict__ ke, char* smem)
{
    float* w2s = (float*)smem;   // 32KB
    const int t = threadIdx.x;
    for (int i = t; i < 8192; i += 256) w2s[i] = w2[i];
    __syncthreads();
    const int row = bid * 16 + (t >> 4);
    const int hh = t & 15;
    const bf16* hr = h + (size_t)row * 512;
    float acc = b2[hh];
    #pragma unroll 8
    for (int j = 0; j < 512; ++j)
        acc = fmaf((float)hr[j], w2s[j * 16 + hh], acc);
    const float gbv = tanhf(acc);
    const int b = row >> 10, n = row & 1023;
    const float c1 = rdb[hh] * LOG2E * (1.0f + ds[(size_t)row * 16 + hh]);
    const float dx = dn[(size_t)row * 4], dy = dn[(size_t)row * 4 + 1], dz = dn[(size_t)row * 4 + 2];
    bf16x8 z = {};
    bf16x8 q0 = z, k0 = z;
    q0[0] = (bf16)(dx * c1); q0[1] = (bf16)(dy * c1); q0[2] = (bf16)(dz * c1); q0[3] = (bf16)1.0f;
    k0[0] = (bf16)dx; k0[1] = (bf16)dy; k0[2] = (bf16)dz; k0[3] = (bf16)(gbv * LOG2E);
    const size_t g = (size_t)(b * 16 + hh) * 1024 + n;
    bf16x8* qp = reinterpret_cast<bf16x8*>(qe + g * 32);
    bf16x8* kp = reinterpret_cast<bf16x8*>(ke + g * 32);
    qp[0] = q0; qp[1] = z; qp[2] = z; qp[3] = z;
    kp[0] = k0; kp[1] = z; kp[2] = z; kp[3] = z;
}

__global__ __launch_bounds__(256) void gemm_k(GJob P)
{
    __shared__ char smem[49152];
    gemm_body(P, blockIdx.x % P.gx, blockIdx.x / P.gx, smem);
}

// ===== wsc combine (0-127) || wcg combine (128-255) || pl23m (256-319) || qkv (320-1855) ==
// small independent segments FIRST so they overlap the long qkv GEMM instead of
// extending its tail (R20/R21 lesson).
__global__ __launch_bounds__(256) void qkvpl_k(GJob P, GJob Pc, GJob Ps2,
    const bf16* __restrict__ h1, const bf16* __restrict__ w2T, const float* __restrict__ b2,
    const bf16* __restrict__ w3T, const float* __restrict__ b3,
    float* __restrict__ pp, bf16* __restrict__ ppb)
{
    __shared__ char smem[49152];
    if (blockIdx.x < 128) gemm_body(Ps2, blockIdx.x % Ps2.gx, blockIdx.x / Ps2.gx, smem);
    else if (blockIdx.x < 256) {
        int id = blockIdx.x - 128;
        gemm_body(Pc, id % Pc.gx, id / Pc.gx, smem);
    } else if (blockIdx.x < 320) pl23m_body(blockIdx.x - 256, h1, w2T, b2, w3T, b3, pp, ppb, smem);
    else {
        int id = blockIdx.x - 320;
        gemm_body(P, id % P.gx, id / P.gx, smem);
    }
}

// ============ gb2x (0-255) || cq GEMM (256-767) || kcv GEMM (768-1791) ============
__global__ __launch_bounds__(256) void gemm2gb_k(GJob P0, GJob P1,
    const bf16* __restrict__ h, const float* __restrict__ w2, const float* __restrict__ b2,
    const float* __restrict__ dn, const float* __restrict__ ds, const float* __restrict__ rdb,
    bf16* __restrict__ qe, bf16* __restrict__ ke)
{
    __shared__ char smem[49152];
    int id = blockIdx.x;
    if (id < 256) gb2x_body(id, h, w2, b2, dn, ds, rdb, qe, ke, smem);
    else if (id < 768) {
        id -= 256;
        gemm_body(P0, id % P0.gx, id / P0.gx, smem);
    } else {
        id -= 768;
        gemm_body(P1, id % P1.gx, id / P1.gx, smem);
    }
}

// ============ XCD-aware block decomposition for attention (512 blocks) ============
__device__ __forceinline__ void attn_bid(int bid, int& bh, int& r0t) {
    const int xcd = bid & 7, s = bid >> 3;
    bh = (s >> 3) * 8 + xcd;
    r0t = s & 7;
}

// ============ MFMA flash self-attention (512 blocks) || spatial diffs (1024 blocks) ======
__global__ __launch_bounds__(512) void attnsd_k(
    const bf16* __restrict__ qb, const bf16* __restrict__ kb, const bf16* __restrict__ vtb,
    const float* __restrict__ relT, bf16* __restrict__ sab,
    const float* __restrict__ pp, bf16* __restrict__ sd)
{
    __shared__ bf16 Ks[2][64 * 64];
    __shared__ bf16 Vs[2][80 * 64];
    __shared__ bf16 Ps[128 * 64];
    __shared__ float relb[2][320];
    const int t = threadIdx.x, w = t >> 6, lane = t & 63;
    if (blockIdx.x >= 512) {
        int g = (blockIdx.x - 512) * 512 + t;
        if (g < B_ * N_ * PP_) {
            const int c = g & 127;
            const int rown = g >> 7;
            const int n = rown & (N_ - 1);
            const int xx = n & 31, yy = (n >> 5) & 31;
            const float cur = pp[g];
            const float hd = (xx < 31) ? fabsf(pp[g + PP_] - cur) : 0.f;
            const float vd = (yy < 31) ? fabsf(pp[g + 32 * PP_] - cur) : 0.f;
            sd[(size_t)rown * 256 + c] = (bf16)hd;
            sd[(size_t)rown * 256 + 128 + c] = (bf16)vd;
        }
        return;
    }
    int bh, r0t;
    attn_bid(blockIdx.x, bh, r0t);
    const int b = bh >> 4, h = bh & 15, r0 = r0t * 128;
    const float* relTh = relT + h * 3969;
    const int y0 = r0 >> 5;

    {   // stage Q (128 rows x 128B) into Ps temp
        const bf16* g = qb + ((size_t)bh * 1024 + r0) * 64;
        #pragma unroll
        for (int r = 0; r < 2; ++r) {
            int i = r * 512 + t;
            int row = i >> 3, c = i & 7;
            const char* src = (const char*)g + (size_t)row * 128 + ((c ^ (row & 7)) << 4);
            gload16(src, Ps + (size_t)(r * 512 + (t & 448)) * 8);
        }
    }
    __syncthreads();
    bf16x8 aq[2];
    {
        const int qr = w * 16 + (lane & 15);
        aq[0] = lds8_swz(Ps, qr, (lane >> 4) * 16);
        aq[1] = lds8_swz(Ps, qr, 64 + (lane >> 4) * 16);
    }
    for (int i = t; i < 2048; i += 512) {
        int buf = i >> 10, idx = i & 1023;
        int row = 64 + (idx >> 6), col = idx & 63;
        Vs[buf][row * 64 + col] = (row == 64) ? (bf16)1.0f : (bf16)0.0f;
    }
    __syncthreads();
    stage64(kb + (size_t)bh * 65536, 128, Ks[0], t);
    stage64(vtb + (size_t)bh * 65536, 2048, Vs[0], t);
    if (t < 320) relb[0][t] = LOG2E * relTh[(y0 + 30 + (t >> 6)) * 63 + min(t & 63, 62)];

    float m_run[4];
    f32x4 of[4], ofe;
    #pragma unroll
    for (int j = 0; j < 4; ++j) m_run[j] = -3e38f;
    #pragma unroll
    for (int dt = 0; dt < 4; ++dt) of[dt] = (f32x4){0.f, 0.f, 0.f, 0.f};
    ofe = (f32x4){0.f, 0.f, 0.f, 0.f};

    const int qrow_lo = (lane >> 4) * 4;
    int dybase[4];
    #pragma unroll
    for (int j = 0; j < 4; ++j) {
        int qg = r0 + w * 16 + qrow_lo + j;
        dybase[j] = (((qg >> 5) - y0) + 1) * 64 + (qg & 31) + 31;
    }
    __syncthreads();

    int cur = 0;
    for (int mt = 0; mt < 16; ++mt) {
        if (mt < 15) {
            stage64(kb + (size_t)bh * 65536 + (size_t)(mt + 1) * 64 * 64, 128, Ks[cur ^ 1], t);
            stage64(vtb + (size_t)bh * 65536 + (size_t)(mt + 1) * 64, 2048, Vs[cur ^ 1], t);
            if (t < 320)
                relb[cur ^ 1][t] = LOG2E * relTh[(y0 - 2 * (mt + 1) + 30 + (t >> 6)) * 63 + min(t & 63, 62)];
        }
        f32x4 sf[4];
        __builtin_amdgcn_s_setprio(1);
        #pragma unroll
        for (int ct = 0; ct < 4; ++ct) {
            const int kr = ct * 16 + (lane & 15);
            f32x4 a = (f32x4){0.f, 0.f, 0.f, 0.f};
            a = MFMA_BF16(aq[0], lds8_swz(Ks[cur], kr, (lane >> 4) * 16), a);
            a = MFMA_BF16(aq[1], lds8_swz(Ks[cur], kr, 64 + (lane >> 4) * 16), a);
            sf[ct] = a;
        }
        __builtin_amdgcn_s_setprio(0);
        float p[4][4], lmax[4];
        #pragma unroll
        for (int j = 0; j < 4; ++j) lmax[j] = -3e38f;
        #pragma unroll
        for (int ct = 0; ct < 4; ++ct) {
            const int xm = (ct & 1) * 16 + (lane & 15);
            const int ro = (ct >> 1) * 64 + xm;
            #pragma unroll
            for (int j = 0; j < 4; ++j) {
                float s = sf[ct][j] + relb[cur][dybase[j] - ro];
                p[ct][j] = s;
                lmax[j] = fmaxf(lmax[j], s);
            }
        }
        bool need = false;
        #pragma unroll
        for (int j = 0; j < 4; ++j) need |= (lmax[j] > m_run[j] + 8.0f);
        if (__any(need)) {
            float mx[4], alpha[4];
            #pragma unroll
            for (int j = 0; j < 4; ++j) mx[j] = lmax[j];
            #pragma unroll
            for (int d = 1; d < 16; d <<= 1)
                #pragma unroll
                for (int j = 0; j < 4; ++j) mx[j] = fmaxf(mx[j], __shfl_xor(mx[j], d));
            #pragma unroll
            for (int j = 0; j < 4; ++j) {
                float mn = fmaxf(m_run[j], mx[j]);
                alpha[j] = exp2f(m_run[j] - mn);
                m_run[j] = mn;
            }
            #pragma unroll
            for (int dt = 0; dt < 4; ++dt)
                #pragma unroll
                for (int j = 0; j < 4; ++j) of[dt][j] *= alpha[j];
            #pragma unroll
            for (int j = 0; j < 4; ++j) ofe[j] *= alpha[j];
        }
        #pragma unroll
        for (int ct = 0; ct < 4; ++ct)
            #pragma unroll
            for (int j = 0; j < 4; ++j)
                p[ct][j] = exp2f(p[ct][j] - m_run[j]);
        #pragma unroll
        for (int ct = 0; ct < 4; ++ct)
            #pragma unroll
            for (int j = 0; j < 4; ++j) {
                const int prow = w * 16 + qrow_lo + j;
                const int ch = (ct * 2 + ((lane & 15) >> 3)) ^ (prow & 7);
                *reinterpret_cast<bf16*>((char*)Ps + prow * 128 + (ch << 4) + (lane & 7) * 2)
                    = (bf16)p[ct][j];
            }
        asm volatile("s_waitcnt lgkmcnt(0)" ::: "memory");
        __builtin_amdgcn_sched_barrier(0);
        bf16x8 ap0 = lds8_swz(Ps, w * 16 + (lane & 15), (lane >> 4) * 16);
        bf16x8 ap1 = lds8_swz(Ps, w * 16 + (lane & 15), 64 + (lane >> 4) * 16);
        __builtin_amdgcn_s_setprio(1);
        #pragma unroll
        for (int dt = 0; dt < 4; ++dt) {
            const int vr = dt * 16 + (lane & 15);
            of[dt] = MFMA_BF16(ap0, lds8_swz(Vs[cur], vr, (lane >> 4) * 16), of[dt]);
            of[dt] = MFMA_BF16(ap1, lds8_swz(Vs[cur], vr, 64 + (lane >> 4) * 16), of[dt]);
        }
        {
            const int vr = 64 + (lane & 15);
            ofe = MFMA_BF16(ap0, lds8_swz(Vs[cur], vr, (lane >> 4) * 16), ofe);
            ofe = MFMA_BF16(ap1, lds8_swz(Vs[cur], vr, 64 + (lane >> 4) * 16), ofe);
        }
        __builtin_amdgcn_s_setprio(0);
        __syncthreads();
        cur ^= 1;
    }
    float inv[4];
    #pragma unroll
    for (int j = 0; j < 4; ++j) inv[j] = 1.f / __shfl(ofe[j], lane & 48);
    #pragma unroll
    for (int dt = 0; dt < 4; ++dt)
        #pragma unroll
        for (int j = 0; j < 4; ++j)
            sab[((size_t)(b * N_ + r0 + w * 16 + qrow_lo + j)) * C_ + h * 64 + dt * 16 + (lane & 15)] =
                (bf16)(of[dt][j] * inv[j]);
}

// ============ MFMA flash cross-attention, ext-K folded biases, lazy softmax ============
__global__ __launch_bounds__(512) void attn_cross_m(
    const bf16* __restrict__ cq, const bf16* __restrict__ qe,
    const bf16* __restrict__ ck, const bf16* __restrict__ ke,
    const bf16* __restrict__ cvt, bf16* __restrict__ cob)
{
    __shared__ bf16 Ks[2][64 * 64];
    __shared__ bf16 Ke[2][32 * 64];
    __shared__ bf16 Vs[2][80 * 64];
    __shared__ bf16 Ps[128 * 64];
    const int t = threadIdx.x, w = t >> 6, lane = t & 63;
    int bh, r0t;
    attn_bid(blockIdx.x, bh, r0t);
    const int b = bh >> 4, h = bh & 15, r0 = r0t * 128;

    {   // stage Q main (128 rows x 128B) into Ps temp
        const bf16* g = cq + ((size_t)bh * 1024 + r0) * 64;
        #pragma unroll
        for (int r = 0; r < 2; ++r) {
            int i = r * 512 + t;
            int row = i >> 3, c = i & 7;
            const char* src = (const char*)g + (size_t)row * 128 + ((c ^ (row & 7)) << 4);
            gload16(src, Ps + (size_t)(r * 512 + (t & 448)) * 8);
        }
    }
    stage64(qe + ((size_t)bh * 1024 + r0) * 32, 128, Ks[0], t);
    __syncthreads();
    bf16x8 aq[2], aqe;
    {
        const int qr = w * 16 + (lane & 15);
        aq[0] = lds8_swz(Ps, qr, (lane >> 4) * 16);
        aq[1] = lds8_swz(Ps, qr, 64 + (lane >> 4) * 16);
        aqe = lds8_ke(Ks[0], qr, lane >> 4);
    }
    for (int i = t; i < 2048; i += 512) {
        int buf = i >> 10, idx = i & 1023;
        int row = 64 + (idx >> 6), col = idx & 63;
        Vs[buf][row * 64 + col] = (row == 64) ? (bf16)1.0f : (bf16)0.0f;
    }
    __syncthreads();
    stage64(ck + (size_t)bh * 65536, 128, Ks[0], t);
    stage32(ke + (size_t)bh * 32768, Ke[0], t);
    stage64(cvt + (size_t)bh * 65536, 2048, Vs[0], t);

    float m_run[4];
    f32x4 of[4], ofe;
    #pragma unroll
    for (int j = 0; j < 4; ++j) m_run[j] = -3e38f;
    #pragma unroll
    for (int dt = 0; dt < 4; ++dt) of[dt] = (f32x4){0.f, 0.f, 0.f, 0.f};
    ofe = (f32x4){0.f, 0.f, 0.f, 0.f};
    const int qrow_lo = (lane >> 4) * 4;
    __syncthreads();

    int cur = 0;
    for (int mt = 0; mt < 16; ++mt) {
        if (mt < 15) {
            stage64(ck + (size_t)bh * 65536 + (size_t)(mt + 1) * 64 * 64, 128, Ks[cur ^ 1], t);
            stage32(ke + (size_t)bh * 32768 + (size_t)(mt + 1) * 64 * 32, Ke[cur ^ 1], t);
            stage64(cvt + (size_t)bh * 65536 + (size_t)(mt + 1) * 64, 2048, Vs[cur ^ 1], t);
        }
        f32x4 sf[4];
        __builtin_amdgcn_s_setprio(1);
        #pragma unroll
        for (int ct = 0; ct < 4; ++ct) {
            const int kr = ct * 16 + (lane & 15);
            f32x4 a = (f32x4){0.f, 0.f, 0.f, 0.f};
            a = MFMA_BF16(aq[0], lds8_swz(Ks[cur], kr, (lane >> 4) * 16), a);
            a = MFMA_BF16(aq[1], lds8_swz(Ks[cur], kr, 64 + (lane >> 4) * 16), a);
            a = MFMA_BF16(aqe, lds8_ke(Ke[cur], kr, lane >> 4), a);
            sf[ct] = a;
        }
        __builtin_amdgcn_s_setprio(0);
        float lmax[4];
        #pragma unroll
        for (int j = 0; j < 4; ++j)
            lmax[j] = fmaxf(fmaxf(sf[0][j], sf[1][j]), fmaxf(sf[2][j], sf[3][j]));
        bool need = false;
        #pragma unroll
        for (int j = 0; j < 4; ++j) need |= (lmax[j] > m_run[j] + 8.0f);
        if (__any(need)) {
            float mx[4], alpha[4];
            #pragma unroll
            for (int j = 0; j < 4; ++j) mx[j] = lmax[j];
            #pragma unroll
            for (int d = 1; d < 16; d <<= 1)
                #pragma unroll
                for (int j = 0; j < 4; ++j) mx[j] = fmaxf(mx[j], __shfl_xor(mx[j], d));
            #pragma unroll
            for (int j = 0; j < 4; ++j) {
                float mn = fmaxf(m_run[j], mx[j]);
                alpha[j] = exp2f(m_run[j] - mn);
                m_run[j] = mn;
            }
            #pragma unroll
            for (int dt = 0; dt < 4; ++dt)
                #pragma unroll
                for (int j = 0; j < 4; ++j) of[dt][j] *= alpha[j];
            #pragma unroll
            for (int j = 0; j < 4; ++j) ofe[j] *= alpha[j];
        }
        #pragma unroll
        for (int ct = 0; ct < 4; ++ct)
            #pragma unroll
            for (int j = 0; j < 4; ++j)
                sf[ct][j] = exp2f(sf[ct][j] - m_run[j]);
        #pragma unroll
        for (int ct = 0; ct < 4; ++ct)
            #pragma unroll
            for (int j = 0; j < 4; ++j) {
                const int prow = w * 16 + qrow_lo + j;
                const int ch = (ct * 2 + ((lane & 15) >> 3)) ^ (prow & 7);
                *reinterpret_cast<bf16*>((char*)Ps + prow * 128 + (ch << 4) + (lane & 7) * 2)
                    = (bf16)sf[ct][j];
            }
        asm volatile("s_waitcnt lgkmcnt(0)" ::: "memory");
        __builtin_amdgcn_sched_barrier(0);
        bf16x8 ap0 = lds8_swz(Ps, w * 16 + (lane & 15), (lane >> 4) * 16);
        bf16x8 ap1 = lds8_swz(Ps, w * 16 + (lane & 15), 64 + (lane >> 4) * 16);
        __builtin_amdgcn_s_setprio(1);
        #pragma unroll
        for (int dt = 0; dt < 4; ++dt) {
            const int vr = dt * 16 + (lane & 15);
            of[dt] = MFMA_BF16(ap0, lds8_swz(Vs[cur], vr, (lane >> 4) * 16), of[dt]);
            of[dt] = MFMA_BF16(ap1, lds8_swz(Vs[cur], vr, 64 + (lane >> 4) * 16), of[dt]);
        }
        {
            const int vr = 64 + (lane & 15);
            ofe = MFMA_BF16(ap0, lds8_swz(Vs[cur], vr, (lane >> 4) * 16), ofe);
            ofe = MFMA_BF16(ap1, lds8_swz(Vs[cur], vr, 64 + (lane >> 4) * 16), ofe);
        }
        __builtin_amdgcn_s_setprio(0);
        __syncthreads();
        cur ^= 1;
    }
    float inv[4];
    #pragma unroll
    for (int j = 0; j < 4; ++j) inv[j] = 1.f / __shfl(ofe[j], lane & 48);
    #pragma unroll
    for (int dt = 0; dt < 4; ++dt)
        #pragma unroll
        for (int j = 0; j < 4; ++j)
            cob[((size_t)(b * N_ + r0 + w * 16 + qrow_lo + j)) * C_ + h * 64 + dt * 16 + (lane & 15)] =
                (bf16)(of[dt][j] * inv[j]);
}

extern "C" void kernel_launch(void* const* d_in, const int* in_sizes, int n_in,
                              void* d_out, int out_size, void* d_ws, size_t ws_size,
                              hipStream_t stream)
{
    const float* x     = (const float*)d_in[0];
    const float* pl    = (const float*)d_in[1];
    const float* w_qkv = (const float*)d_in[2];
    const float* w_sp  = (const float*)d_in[3];
    const float* b_sp  = (const float*)d_in[4];
    const float* pl_w1 = (const float*)d_in[5];
    const float* pl_b1 = (const float*)d_in[6];
    const float* pl_w2 = (const float*)d_in[7];
    const float* pl_b2 = (const float*)d_in[8];
    const float* pl_w3 = (const float*)d_in[9];
    const float* pl_b3 = (const float*)d_in[10];
    const float* w_cq  = (const float*)d_in[11];
    const float* w_pk  = (const float*)d_in[12];
    const float* w_pv  = (const float*)d_in[13];
    const float* w_cp  = (const float*)d_in[14];
    const float* b_cp  = (const float*)d_in[15];
    const float* rdb   = (const float*)d_in[16];
    const float* ds_w1 = (const float*)d_in[17];
    const float* ds_b1 = (const float*)d_in[18];
    const float* ds_w2 = (const float*)d_in[19];
    const float* ds_b2 = (const float*)d_in[20];
    const float* gb_w1 = (const float*)d_in[21];
    const float* gb_b1 = (const float*)d_in[22];
    const float* gb_w2 = (const float*)d_in[23];
    const float* gb_b2 = (const float*)d_in[24];
    const float* rel_t = (const float*)d_in[25];
    const float* gfw1  = (const float*)d_in[26];
    const float* gfb1  = (const float*)d_in[27];
    const float* gfw2  = (const float*)d_in[28];
    const float* gfb2  = (const float*)d_in[29];

    char* W = (char*)d_ws;
    float* out = (float*)d_out;
    const size_t MB = 1ull << 20;
    const size_t KB = 1024;

    bf16* qb     = (bf16*)(W + 0);           // 8MB ; cqb reuses
    bf16* kb     = (bf16*)(W + 8 * MB);      // 8MB ; ckb reuses
    bf16* vtb    = (bf16*)(W + 16 * MB);     // 8MB ; cvtb reuses
    bf16* cqb    = qb;
    bf16* ckb    = kb;
    bf16* cvtb   = vtb;
    bf16* xb     = (bf16*)(W + 24 * MB);     // 8MB
    bf16* wqkvT  = (bf16*)(W + 32 * MB);     // 6MB
    bf16* wspB   = (bf16*)(W + 38 * MB);     // 2MB (plain cast of w_sp)
    bf16* wcqT   = (bf16*)(W + 40 * MB);     // 2MB
    bf16* wpkT   = (bf16*)(W + 42 * MB);               // 256KB
    bf16* wpvT   = (bf16*)(W + 42 * MB + 256 * KB);    // 256KB (contiguous after wpkT)
    bf16* wcpB   = (bf16*)(W + 43 * MB);     // 2MB (plain cast of w_cp)
    bf16* gf1tT  = (bf16*)(W + 45 * MB);     // 2MB (gfw1 top 1024 rows, transposed)
    bf16* gf1bT  = (bf16*)(W + 47 * MB);     // 256KB (gfw1 bottom 128 rows, transposed)
    bf16* gfw2T  = (bf16*)(W + 48 * MB);     // 2MB
    bf16* gbw1T  = (bf16*)(W + 50 * MB);               // 256KB
    bf16* plw2T  = (bf16*)(W + 50 * MB + 256 * KB);    // 64KB
    bf16* plw3T  = (bf16*)(W + 50 * MB + 320 * KB);    // 32KB
    bf16* sab    = (bf16*)(W + 51 * MB);     // 8MB ; cob reuses
    bf16* cob    = sab;
    float* pp    = (float*)(W + 67 * MB);    // 2MB
    bf16* ppb    = (bf16*)(W + 69 * MB);     // 1MB
    bf16* sdb16  = (bf16*)(W + 70 * MB);     // 2MB
    bf16* h1b    = (bf16*)(W + 72 * MB);     // 2MB
    bf16* gbh    = (bf16*)(W + 75 * MB);     // 4MB
    float* dsb   = (float*)(W + 79 * MB);              // 256KB
    float* dnb   = (float*)(W + 79 * MB + 256 * KB);   // 64KB
    float2* rtab = (float2*)(W + 80 * MB);             // 256KB
    float* relTb = (float*)(W + 80 * MB + 256 * KB);   // 254KB
    bf16* hidb   = (bf16*)(W + 81 * MB);     // 8MB
    bf16* qeb    = (bf16*)(W + 89 * MB);     // 4MB [64][1024][32]
    bf16* keb    = (bf16*)(W + 93 * MB);     // 4MB
    bf16* wcgT   = (bf16*)(W + 97 * MB);     // 2MB (combined (w_cp@gfw1_top)^T)
    float* bscgb = (float*)(W + 99 * MB);              // 4KB
    float* bscb  = (float*)(W + 99 * MB + 8 * KB);     // 4KB
    bf16* wscT   = (bf16*)(W + 100 * MB);    // 2MB (combined (w_sp@w_cq)^T) -> 102MB total

    const dim3 blk(256);

    TJobs J;
    J.src[0] = w_qkv;              J.dst[0] = wqkvT; J.K[0] = 1024; J.N[0] = 3072;
    J.src[1] = w_cq;               J.dst[1] = wcqT;  J.K[1] = 1024; J.N[1] = 1024;
    J.src[2] = w_pk;               J.dst[2] = wpkT;  J.K[2] = 128;  J.N[2] = 1024;
    J.src[3] = w_pv;               J.dst[3] = wpvT;  J.K[3] = 128;  J.N[3] = 1024;
    J.src[4] = gfw1;               J.dst[4] = gf1tT; J.K[4] = 1024; J.N[4] = 1024;
    J.src[5] = gfw1 + 1024 * 1024; J.dst[5] = gf1bT; J.K[5] = 128;  J.N[5] = 1024;
    J.src[6] = gfw2;               J.dst[6] = gfw2T; J.K[6] = 1024; J.N[6] = 1024;
    J.src[7] = gb_w1;              J.dst[7] = gbw1T; J.K[7] = 256;  J.N[7] = 512;
    J.src[8] = pl_w2;              J.dst[8] = plw2T; J.K[8] = 256;  J.N[8] = 128;
    J.src[9] = pl_w3;              J.dst[9] = plw3T; J.K[9] = 128;  J.N[9] = 128;
    {
        int acc = 0;
        for (int j = 0; j < 10; ++j) {
            J.base[j] = acc;
            acc += (J.N[j] >> 5) * (J.K[j] >> 5);
        }
        J.base[10] = acc;
    }
    const int pre_blocks = J.base[10] + 4096 + 512 + 377 + 32 + 1024;

    auto mkjob = [](const bf16* A, const bf16* A2, const bf16* Bt, const bf16* Bt2,
                    const float* bias, const float* resid,
                    void* o0, void* o1, void* o2, const float2* rt,
                    int N, int K, int K1A, int K1B, int epi, int ag, int gx, float sc) {
        GJob g;
        g.A = A; g.A2 = A2; g.Bt = Bt; g.Bt2 = Bt2; g.bias = bias; g.resid = resid;
        g.out0 = o0; g.out1 = o1; g.out2 = o2; g.rtab = rt;
        g.N = N; g.K = K; g.K1A = K1A; g.K1B = K1B; g.epi = epi; g.act_gelu = ag;
        g.gx = gx; g.scale = sc;
        return g;
    };

    // 1. merged preamble (+ w_cp/w_sp casts + bscg/bsc GEMVs)
    pre_k<<<pre_blocks, blk, 0, stream>>>(J, x, xb, w_cp, wcpB, w_sp, wspB,
        rel_t, relTb, rtab, b_cp, gfw1, gfb1, bscgb, b_sp, w_cq, bscb,
        pl, pl_w1, pl_b1, ds_w1, ds_b1, ds_w2, ds_b2, h1b, dsb, dnb);
    // 2. wsc combine || wcg combine || pl23m || qkv GEMM (small segments first)
    GJob jqkv = mkjob(xb, nullptr, wqkvT, nullptr, nullptr, nullptr,
                      qb, kb, vtb, rtab, 3072, 1024, 1024, 1024, 2, 0, 48, 0.125f * LOG2E);
    GJob jwcg = mkjob(gf1tT, nullptr, wcpB, nullptr, nullptr, nullptr,
                      wcgT, nullptr, nullptr, nullptr, 1024, 1024, 1024, 1024, 1, 0, 16, 1.f);
    GJob jwsc = mkjob(wcqT, nullptr, wspB, nullptr, nullptr, nullptr,
                      wscT, nullptr, nullptr, nullptr, 1024, 1024, 1024, 1024, 1, 0, 16, 1.f);
    qkvpl_k<<<128 + 128 + 64 + 1536, blk, 0, stream>>>(jqkv, jwcg, jwsc,
        h1b, plw2T, pl_b2, plw3T, pl_b3, pp, ppb);
    // 3. self attention || spatial diffs
    attnsd_k<<<512 + 1024, dim3(512), 0, stream>>>(qb, kb, vtb, relTb, sab, pp, sdb16);
    // 4. gb layer1 (gelu)  [self-proj folded away]
    GJob jgb1 = mkjob(sdb16, nullptr, gbw1T, nullptr, gb_b1, nullptr,
                      gbh, nullptr, nullptr, nullptr, 512, 256, 256, 256, 1, 1, 8, 1.f);
    gemm_k<<<256, blk, 0, stream>>>(jgb1);
    // 5. tri launch: gb2x first, then cq = rope(sa@wsc + bsc)*(dsr scale) || ck+cv split
    GJob jcq  = mkjob(sab, nullptr, wscT, nullptr, bscb, dsb,
                      cqb, nullptr, nullptr, rtab, 1024, 1024, 1024, 1024, 6, 0, 16, 0.125f * LOG2E);
    GJob jkcv = mkjob(ppb, nullptr, wpkT, nullptr, nullptr, nullptr,
                      ckb, nullptr, cvtb, rtab, 2048, 128, 128, 128, 7, 0, 32, 1.f);
    gemm2gb_k<<<256 + 512 + 1024, blk, 0, stream>>>(jcq, jkcv,
        gbh, gb_w2, gb_b2, dnb, dsb, rdb, qeb, keb);
    // 6. cross attention
    attn_cross_m<<<512, dim3(512), 0, stream>>>(cqb, qeb, ckb, keb, cvtb, cob);
    // 7. gfe1 with folded cross-proj: gelu(cob@wcgT^T + pp@gf1bT^T + bscg)
    GJob jg1 = mkjob(cob, ppb, wcgT, gf1bT, bscgb, nullptr,
                     hidb, nullptr, nullptr, nullptr, 1024, 1152, 1024, 1024, 1, 1, 16, 1.f);
    gemm_k<<<512, blk, 0, stream>>>(jg1);
    // 8. gfe2 + bias + residual -> fp32 out
    GJob jg2 = mkjob(hidb, nullptr, gfw2T, nullptr, gfb2, x,
                     out, nullptr, nullptr, nullptr, 1024, 1024, 1024, 1024, 0, 0, 16, 1.f);
    gemm_k<<<512, blk, 0, stream>>>(jg2);
}

// Round 27
// 281.523 us; speedup vs baseline: 1.0518x; 1.0016x over previous
//
#include <hip/hip_runtime.h>
#include <math.h>

#define B_ 4
#define N_ 1024
#define C_ 1024
#define NH_ 16
#define HD_ 64
#define PP_ 128
#define LOG2E 1.4426950408889634f

typedef __bf16 bf16;
typedef __attribute__((ext_vector_type(8))) __bf16 bf16x8;
typedef __attribute__((ext_vector_type(4))) __bf16 bf16x4;
typedef __attribute__((ext_vector_type(4))) float f32x4;

#define MFMA_BF16(a, b, c) __builtin_amdgcn_mfma_f32_16x16x32_bf16((a), (b), (c), 0, 0, 0)

__device__ __forceinline__ float gelu_f(float x) {
    return 0.5f * x * (1.0f + erff(x * 0.70710678118654752f));
}

__device__ __forceinline__ void gload16(const void* g, void* l) {
    __builtin_amdgcn_global_load_lds(
        (const __attribute__((address_space(1))) void*)g,
        (__attribute__((address_space(3))) void*)l, 16, 0, 0);
}

// stage a 64-row x 128B tile into LDS, XOR-swizzled source, 512 threads (1 chunk each)
__device__ __forceinline__ void stage64(const bf16* __restrict__ g, int pitchB,
                                        bf16* lds, int t) {
    int row = t >> 3, c = t & 7;
    const char* src = (const char*)g + (size_t)row * pitchB + ((c ^ (row & 7)) << 4);
    gload16(src, lds + (size_t)(t & 448) * 8);
}

// stage a 32-row x 128B tile (ext: 64 k-rows x 64B packed 2-per-LDS-row), 256 of 512 threads
__device__ __forceinline__ void stage32(const bf16* __restrict__ g, bf16* lds, int t) {
    if (t < 256) {
        int row = t >> 3, c = t & 7;
        const char* src = (const char*)g + (size_t)row * 128 + ((c ^ (row & 7)) << 4);
        gload16(src, lds + (size_t)(t & 192) * 8);
    }
}

__device__ __forceinline__ bf16x8 lds8_swz(const bf16* lds, int row, int colb) {
    return *reinterpret_cast<const bf16x8*>(
        (const char*)lds + row * 128 + (colb ^ ((row & 7) << 4)));
}

// 256B-row variant (for pl23m tiles)
__device__ __forceinline__ bf16x8 lds8_swz256(const bf16* lds, int row, int colb) {
    return *reinterpret_cast<const bf16x8*>(
        (const char*)lds + row * 256 + (colb ^ ((row & 7) << 4)));
}

// read 16B of ext row kr (64B rows packed 2-per-LDS-row), chunk g in 0..3
__device__ __forceinline__ bf16x8 lds8_ke(const bf16* lds, int kr, int g) {
    int r = kr >> 1;
    int ch = ((kr & 1) * 4 + g) ^ (r & 7);
    return *reinterpret_cast<const bf16x8*>((const char*)lds + r * 128 + (ch << 4));
}

// ============ transpose-cast job table (10 jobs) ============
struct TJobs {
    const float* src[11];
    bf16* dst[11];
    int K[11];
    int N[11];
    int base[12];   // prefix tile offsets; base[10] = total tiles
};

// ===== merged preamble: tcast | cast x | cast w_cp | cast w_sp | tables | bscg | bsc | pl1
__global__ __launch_bounds__(256) void pre_k(
    TJobs J, const float* __restrict__ x, bf16* __restrict__ xb,
    const float* __restrict__ w_cp, bf16* __restrict__ wcpB,
    const float* __restrict__ w_sp, bf16* __restrict__ wspB,
    const float* __restrict__ rel_table, float* __restrict__ relT, float2* __restrict__ rt,
    const float* __restrict__ b_cp, const float* __restrict__ gfw1,
    const float* __restrict__ gfb1, float* __restrict__ bscg,
    const float* __restrict__ b_sp, const float* __restrict__ w_cq, float* __restrict__ bsc,
    const float* __restrict__ pl,
    const float* __restrict__ w1, const float* __restrict__ b1,
    const float* __restrict__ dw1, const float* __restrict__ db1,
    const float* __restrict__ dw2, const float* __restrict__ db2,
    bf16* __restrict__ h1b, float* __restrict__ ds, float* __restrict__ dn)
{
    __shared__ float tl[32][33];
    __shared__ float plr[6];
    __shared__ float dh[64];
    __shared__ float red[4][64];
    const int t = threadIdx.x;
    const int bid = blockIdx.x;
    const int ntc = J.base[10];
    if (bid < ntc) {
        int tile = bid;
        int j = 0;
        while (j + 1 < 10 && tile >= J.base[j + 1]) ++j;
        tile -= J.base[j];
        const int Kd = J.K[j], Nd = J.N[j];
        const int ntx = Nd >> 5;
        const int n0 = (tile % ntx) * 32, k0 = (tile / ntx) * 32;
        const int tx = t & 31, ty = t >> 5;
        const float* src = J.src[j];
        bf16* dst = J.dst[j];
        #pragma unroll
        for (int r = 0; r < 4; ++r) {
            int kk = ty + r * 8;
            tl[kk][tx] = src[(size_t)(k0 + kk) * Nd + n0 + tx];
        }
        __syncthreads();
        #pragma unroll
        for (int r = 0; r < 4; ++r) {
            int nn = ty + r * 8;
            dst[(size_t)(n0 + nn) * Kd + k0 + tx] = (bf16)tl[tx][nn];
        }
    } else if (bid < ntc + 4096) {
        int g = (bid - ntc) * 256 + t;
        float4 v = reinterpret_cast<const float4*>(x)[g];
        bf16x4 o = {(bf16)v.x, (bf16)v.y, (bf16)v.z, (bf16)v.w};
        reinterpret_cast<bf16x4*>(xb)[g] = o;
    } else if (bid < ntc + 4096 + 256) {
        int g = (bid - ntc - 4096) * 256 + t;
        float4 v = reinterpret_cast<const float4*>(w_cp)[g];
        bf16x4 o = {(bf16)v.x, (bf16)v.y, (bf16)v.z, (bf16)v.w};
        reinterpret_cast<bf16x4*>(wcpB)[g] = o;
    } else if (bid < ntc + 4096 + 512) {
        int g = (bid - ntc - 4096 - 256) * 256 + t;
        float4 v = reinterpret_cast<const float4*>(w_sp)[g];
        bf16x4 o = {(bf16)v.x, (bf16)v.y, (bf16)v.z, (bf16)v.w};
        reinterpret_cast<bf16x4*>(wspB)[g] = o;
    } else if (bid < ntc + 4096 + 512 + 377) {
        int g = (bid - ntc - 4096 - 512) * 256 + t;
        if (g < 32768) {
            const int n = g >> 5, i = g & 31;
            const float inv = powf(10000.0f, -(float)(2 * i) / 64.0f);
            const float ang = (float)n * inv;
            rt[g] = make_float2(cosf(ang), sinf(ang));
        } else {
            int i = g - 32768;
            if (i < 16 * 3969) {
                int h = i / 3969, idx = i - h * 3969;
                relT[i] = rel_table[idx * 16 + h];
            }
        }
    } else if (bid < ntc + 4096 + 512 + 377 + 16) {
        // bscg[c] = gfb1[c] + sum_{j<1024} b_cp[j] * gfw1[j][c]
        const int pb = bid - ntc - 4096 - 512 - 377;
        const int c = pb * 64 + (t & 63);
        const int js = t >> 6;
        float a = 0.f;
        #pragma unroll 8
        for (int j = js * 256; j < js * 256 + 256; ++j)
            a = fmaf(b_cp[j], gfw1[(size_t)j * 1024 + c], a);
        red[js][t & 63] = a;
        __syncthreads();
        if (t < 64) {
            int cc = pb * 64 + t;
            bscg[cc] = red[0][t] + red[1][t] + red[2][t] + red[3][t] + gfb1[cc];
        }
    } else if (bid < ntc + 4096 + 512 + 377 + 32) {
        // bsc[c] = sum_{j<1024} b_sp[j] * w_cq[j][c]
        const int pb = bid - ntc - 4096 - 512 - 377 - 16;
        const int c = pb * 64 + (t & 63);
        const int js = t >> 6;
        float a = 0.f;
        #pragma unroll 8
        for (int j = js * 256; j < js * 256 + 256; ++j)
            a = fmaf(b_sp[j], w_cq[(size_t)j * 1024 + c], a);
        red[js][t & 63] = a;
        __syncthreads();
        if (t < 64) {
            int cc = pb * 64 + t;
            bsc[cc] = red[0][t] + red[1][t] + red[2][t] + red[3][t];
        }
    } else {
        const int pb = bid - ntc - 4096 - 512 - 377 - 32;
        #pragma unroll 1
        for (int rr = 0; rr < 4; ++rr) {
            const int row = pb * 4 + rr;
            if (t < 6) plr[t] = pl[(size_t)row * 6 + t];
            __syncthreads();
            {
                float a = b1[t];
                #pragma unroll
                for (int j = 0; j < 6; ++j) a = fmaf(plr[j], w1[j * 256 + t], a);
                h1b[(size_t)row * 256 + t] = (bf16)gelu_f(a);
            }
            if (t < 64) {
                float d = db1[t];
                #pragma unroll
                for (int j = 0; j < 6; ++j) d = fmaf(plr[j], dw1[j * 64 + t], d);
                dh[t] = gelu_f(d);
            }
            if (t == 0) {
                float xx = plr[0], yy = plr[1], zz = plr[2];
                float nrm = fmaxf(sqrtf(xx * xx + yy * yy + zz * zz), 1e-12f);
                dn[(size_t)row * 4 + 0] = xx / nrm;
                dn[(size_t)row * 4 + 1] = yy / nrm;
                dn[(size_t)row * 4 + 2] = zz / nrm;
                dn[(size_t)row * 4 + 3] = 0.f;
            }
            __syncthreads();
            if (t < 16) {
                float d = db2[t];
                #pragma unroll 8
                for (int j = 0; j < 64; ++j) d = fmaf(dh[j], dw2[j * 16 + t], d);
                ds[(size_t)row * 16 + t] = tanhf(d);
            }
            __syncthreads();
        }
    }
}

// ============ GEMM job descriptor ============
struct GJob {
    const bf16* A; const bf16* A2; const bf16* Bt; const bf16* Bt2;
    const float* bias; const float* resid;
    void* out0; void* out1; void* out2;
    const float2* rtab;
    int N, K, K1A, K1B, epi, act_gelu, gx;
    float scale;
};

// ============ MFMA GEMM body, 128x64 tile, BK=64, 2-phase double-buffered ============
__device__ __forceinline__ void gemm_body(const GJob& P, int bx, int by, char* smem)
{
    const bf16* A = P.A; const bf16* A2 = P.A2;
    const bf16* Bt = P.Bt; const bf16* Bt2 = P.Bt2;
    const float* bias = P.bias; const float* resid = P.resid;
    void* out0 = P.out0; void* out1 = P.out1; void* out2 = P.out2;
    const float2* rtab = P.rtab;
    const int N = P.N, K = P.K, K1A = P.K1A, K1B = P.K1B;
    const int epi = P.epi, act_gelu = P.act_gelu;
    const float scale = P.scale;

    bf16 (*As)[128 * 64] = (bf16(*)[128 * 64])smem;
    bf16 (*Bs)[64 * 64]  = (bf16(*)[64 * 64])(smem + 32768);
    const int t = threadIdx.x;
    const int w = t >> 6, lane = t & 63;
    const int row0 = by * 128, col0 = bx * 64;
    const int wm = w >> 1, wn = w & 1;
    const int K2A = K - K1A, K2B = K - K1B;
    f32x4 acc[4][2];
    #pragma unroll
    for (int mi = 0; mi < 4; ++mi)
        #pragma unroll
        for (int ni = 0; ni < 2; ++ni)
            acc[mi][ni] = (f32x4){0.f, 0.f, 0.f, 0.f};

    #define STAGE_AB64(k0, buf)                                                \
        {                                                                      \
            const bf16* abase; int apitch;                                     \
            if ((k0) < K1A) { abase = A + (k0); apitch = K1A; }                \
            else            { abase = A2 + ((k0) - K1A); apitch = K2A; }       \
            _Pragma("unroll")                                                  \
            for (int r = 0; r < 4; ++r) {                                      \
                int c = r * 256 + t;                                           \
                int rr = c >> 3, cc = c & 7;                                   \
                const char* srca = (const char*)(abase + (size_t)(row0 + rr) * apitch) \
                                   + ((cc ^ (rr & 7)) << 4);                   \
                gload16(srca, As[buf] + (size_t)(r * 256 + (t & 192)) * 8);    \
            }                                                                  \
            const bf16* bbase; int bpitch;                                     \
            if ((k0) < K1B) { bbase = Bt + (k0); bpitch = K1B; }               \
            else            { bbase = Bt2 + ((k0) - K1B); bpitch = K2B; }      \
            _Pragma("unroll")                                                  \
            for (int r = 0; r < 2; ++r) {                                      \
                int c = r * 256 + t;                                           \
                int rr = c >> 3, cc = c & 7;                                   \
                const char* srcb = (const char*)(bbase + (size_t)(col0 + rr) * bpitch) \
                                   + ((cc ^ (rr & 7)) << 4);                   \
                gload16(srcb, Bs[buf] + (size_t)(r * 256 + (t & 192)) * 8);    \
            }                                                                  \
        }

    int cur = 0;
    const int nk = K >> 6;
    STAGE_AB64(0, 0);
    __syncthreads();
    for (int kk = 0; kk < nk; ++kk) {
        if (kk + 1 < nk) STAGE_AB64((kk + 1) * 64, cur ^ 1);
        bf16x8 af[4][2], bfv[2][2];
        #pragma unroll
        for (int mi = 0; mi < 4; ++mi)
            #pragma unroll
            for (int kh = 0; kh < 2; ++kh)
                af[mi][kh] = lds8_swz(As[cur], wm * 64 + mi * 16 + (lane & 15),
                                      kh * 64 + (lane >> 4) * 16);
        #pragma unroll
        for (int ni = 0; ni < 2; ++ni)
            #pragma unroll
            for (int kh = 0; kh < 2; ++kh)
                bfv[ni][kh] = lds8_swz(Bs[cur], wn * 32 + ni * 16 + (lane & 15),
                                       kh * 64 + (lane >> 4) * 16);
        #pragma unroll
        for (int kh = 0; kh < 2; ++kh)
            #pragma unroll
            for (int mi = 0; mi < 4; ++mi)
                #pragma unroll
                for (int ni = 0; ni < 2; ++ni)
                    acc[mi][ni] = MFMA_BF16(af[mi][kh], bfv[ni][kh], acc[mi][ni]);
        __syncthreads();
        cur ^= 1;
    }
    #undef STAGE_AB64

    #pragma unroll
    for (int mi = 0; mi < 4; ++mi) {
        #pragma unroll
        for (int ni = 0; ni < 2; ++ni) {
            const int col = col0 + wn * 32 + ni * 16 + (lane & 15);
            if (epi <= 1 || epi == 5) {
                const float bv = bias ? bias[col] : 0.f;
                #pragma unroll
                for (int j = 0; j < 4; ++j) {
                    const int row = row0 + wm * 64 + mi * 16 + (lane >> 4) * 4 + j;
                    float v = acc[mi][ni][j] + bv;
                    if (act_gelu) v = gelu_f(v);
                    if (epi == 0) {
                        if (resid) v += resid[(size_t)row * N + col];
                        ((float*)out0)[(size_t)row * N + col] = v;
                    } else if (epi == 1) {
                        ((bf16*)out0)[(size_t)row * N + col] = (bf16)v;
                    } else {
                        ((float*)out0)[(size_t)row * N + col] = v;
                        ((bf16*)out1)[(size_t)row * N + col] = (bf16)v;
                    }
                }
            } else if (epi == 2) {
                const int reg = col >> 10;         // 0=q 1=k 2=v
                const int h = (col >> 6) & 15, d = col & 63;
                if (reg <= 1) {
                    bf16* dst = reg == 0 ? (bf16*)out0 : (bf16*)out1;
                    const float sc = reg == 0 ? scale : 1.0f;
                    #pragma unroll
                    for (int j = 0; j < 4; ++j) {
                        const int row = row0 + wm * 64 + mi * 16 + (lane >> 4) * 4 + j;
                        const int b = row >> 10, n = row & 1023;
                        float v = acc[mi][ni][j];
                        float pv = __shfl_xor(v, 1);
                        float2 cs = rtab[(n << 5) + (d >> 1)];
                        float o = (d & 1) == 0 ? v * cs.x - pv * cs.y
                                               : v * cs.x + pv * cs.y;
                        dst[((size_t)((b * 16 + h) * 1024 + n)) * 64 + d] = (bf16)(o * sc);
                    }
                } else {
                    bf16x4 o4;
                    #pragma unroll
                    for (int j = 0; j < 4; ++j) o4[j] = (bf16)acc[mi][ni][j];
                    const int row = row0 + wm * 64 + mi * 16 + (lane >> 4) * 4;
                    const int b = row >> 10, n = row & 1023;
                    *reinterpret_cast<bf16x4*>(
                        (bf16*)out2 + ((size_t)((b * 16 + h) * 64 + d)) * 1024 + n) = o4;
                }
            } else if (epi == 3 || epi == 6) {
                const int h = (col >> 6) & 15, d = col & 63;
                const float bv = bias ? bias[col] : 0.f;
                #pragma unroll
                for (int j = 0; j < 4; ++j) {
                    const int row = row0 + wm * 64 + mi * 16 + (lane >> 4) * 4 + j;
                    const int b = row >> 10, n = row & 1023;
                    float v = acc[mi][ni][j] + bv;
                    float pv = __shfl_xor(v, 1);
                    float2 cs = rtab[(n << 5) + (d >> 1)];
                    float o = (d & 1) == 0 ? v * cs.x - pv * cs.y
                                           : v * cs.x + pv * cs.y;
                    float sc = scale;
                    if (epi == 6) sc *= 1.0f + resid[(size_t)row * 16 + h];
                    ((bf16*)out0)[((size_t)((b * 16 + h) * 1024 + n)) * 64 + d] = (bf16)(o * sc);
                }
            } else if (epi == 7) {
                const int reg = col >> 10;         // 0=ck(rope) 1=cv(transposed)
                const int h = (col >> 6) & 15, d = col & 63;
                if (reg == 0) {
                    #pragma unroll
                    for (int j = 0; j < 4; ++j) {
                        const int row = row0 + wm * 64 + mi * 16 + (lane >> 4) * 4 + j;
                        const int b = row >> 10, n = row & 1023;
                        float v = acc[mi][ni][j];
                        float pv = __shfl_xor(v, 1);
                        float2 cs = rtab[(n << 5) + (d >> 1)];
                        float o = (d & 1) == 0 ? v * cs.x - pv * cs.y
                                               : v * cs.x + pv * cs.y;
                        ((bf16*)out0)[((size_t)((b * 16 + h) * 1024 + n)) * 64 + d] = (bf16)o;
                    }
                } else {
                    bf16x4 o4;
                    #pragma unroll
                    for (int j = 0; j < 4; ++j) o4[j] = (bf16)acc[mi][ni][j];
                    const int row = row0 + wm * 64 + mi * 16 + (lane >> 4) * 4;
                    const int b = row >> 10, n = row & 1023;
                    *reinterpret_cast<bf16x4*>(
                        (bf16*)out2 + ((size_t)((b * 16 + h) * 64 + d)) * 1024 + n) = o4;
                }
            } else {  // epi == 4: transposed head-major
                const int h = (col >> 6) & 15, d = col & 63;
                bf16x4 o4;
                #pragma unroll
                for (int j = 0; j < 4; ++j) o4[j] = (bf16)acc[mi][ni][j];
                const int row = row0 + wm * 64 + mi * 16 + (lane >> 4) * 4;
                const int b = row >> 10, n = row & 1023;
                *reinterpret_cast<bf16x4*>(
                    (bf16*)out0 + ((size_t)((b * 16 + h) * 64 + d)) * 1024 + n) = o4;
            }
        }
    }
}

// ============ plucker layers 2+3 body (uses 48KB smem) ============
__device__ __forceinline__ void pl23m_body(
    int bid, const bf16* __restrict__ h1, const bf16* __restrict__ w2T,
    const float* __restrict__ b2, const bf16* __restrict__ w3T, const float* __restrict__ b3,
    float* __restrict__ pp, bf16* __restrict__ ppb, char* smem)
{
    bf16* Am = (bf16*)smem;              // 16KB
    bf16* Wm = (bf16*)(smem + 16384);    // 32KB
    const int t = threadIdx.x, w = t >> 6, lane = t & 63;
    const int row0 = bid * 64;
    f32x4 acc[8];
    #pragma unroll
    for (int nt = 0; nt < 8; ++nt) acc[nt] = (f32x4){0.f, 0.f, 0.f, 0.f};

    for (int kc = 0; kc < 2; ++kc) {
        #pragma unroll
        for (int r = 0; r < 4; ++r) {
            int i = r * 256 + t;
            int row = i >> 4, c = i & 15;
            const char* src = (const char*)(h1 + (size_t)(row0 + row) * 256 + kc * 128)
                              + ((c ^ (row & 7)) << 4);
            gload16(src, Am + (size_t)(r * 256 + (t & 192)) * 8);
        }
        #pragma unroll
        for (int r = 0; r < 8; ++r) {
            int i = r * 256 + t;
            int row = i >> 4, c = i & 15;
            const char* src = (const char*)(w2T + (size_t)row * 256 + kc * 128)
                              + ((c ^ (row & 7)) << 4);
            gload16(src, Wm + (size_t)(r * 256 + (t & 192)) * 8);
        }
        __syncthreads();
        #pragma unroll
        for (int step = 0; step < 4; ++step) {
            bf16x8 af = lds8_swz256(Am, w * 16 + (lane & 15), step * 64 + (lane >> 4) * 16);
            #pragma unroll
            for (int nt = 0; nt < 8; ++nt) {
                bf16x8 bfv = lds8_swz256(Wm, nt * 16 + (lane & 15), step * 64 + (lane >> 4) * 16);
                acc[nt] = MFMA_BF16(af, bfv, acc[nt]);
            }
        }
        __syncthreads();
    }
    #pragma unroll
    for (int r = 0; r < 8; ++r) {
        int i = r * 256 + t;
        int row = i >> 4, c = i & 15;
        const char* src = (const char*)(w3T + (size_t)row * 128) + ((c ^ (row & 7)) << 4);
        gload16(src, Wm + (size_t)(r * 256 + (t & 192)) * 8);
    }
    #pragma unroll
    for (int nt = 0; nt < 8; ++nt) {
        const int col = nt * 16 + (lane & 15);
        const float bv = b2[col];
        #pragma unroll
        for (int j = 0; j < 4; ++j) {
            const int row = w * 16 + (lane >> 4) * 4 + j;
            const int byte = row * 256 + (((col * 2) & ~15) ^ ((row & 7) << 4)) + ((col * 2) & 15);
            *reinterpret_cast<bf16*>((char*)Am + byte) = (bf16)gelu_f(acc[nt][j] + bv);
        }
    }
    __syncthreads();
    f32x4 acc2[8];
    #pragma unroll
    for (int nt = 0; nt < 8; ++nt) acc2[nt] = (f32x4){0.f, 0.f, 0.f, 0.f};
    #pragma unroll
    for (int step = 0; step < 4; ++step) {
        bf16x8 af = lds8_swz256(Am, w * 16 + (lane & 15), step * 64 + (lane >> 4) * 16);
        #pragma unroll
        for (int nt = 0; nt < 8; ++nt) {
            bf16x8 bfv = lds8_swz256(Wm, nt * 16 + (lane & 15), step * 64 + (lane >> 4) * 16);
            acc2[nt] = MFMA_BF16(af, bfv, acc2[nt]);
        }
    }
    #pragma unroll
    for (int nt = 0; nt < 8; ++nt) {
        const int col = nt * 16 + (lane & 15);
        const float bv = b3[col];
        #pragma unroll
        for (int j = 0; j < 4; ++j) {
            const int row = row0 + w * 16 + (lane >> 4) * 4 + j;
            const float v = acc2[nt][j] + bv;
            pp[(size_t)row * 128 + col] = v;
            ppb[(size_t)row * 128 + col] = (bf16)v;
        }
    }
}

// ============ gb layer2 body (uses 32KB of smem) ============
__device__ __forceinline__ void gb2x_body(
    int bid, const bf16* __restrict__ h, const float* __restrict__ w2,
    const float* __restrict__ b2, const float* __restrict__ dn,
    const float* __restrict__ ds, const float* __restrict__ rdb,
    bf16* __restrict__ qe, bf16* __restrict__ ke, char* smem)
{
    float* w2s = (float*)smem;   // 32KB
    const int t = threadIdx.x;
    for (int i = t; i < 8192; i += 256) w2s[i] = w2[i];
    __syncthreads();
    const int row = bid * 16 + (t >> 4);
    const int hh = t & 15;
    const bf16* hr = h + (size_t)row * 512;
    float acc = b2[hh];
    #pragma unroll 8
    for (int j = 0; j < 512; ++j)
        acc = fmaf((float)hr[j], w2s[j * 16 + hh], acc);
    const float gbv = tanhf(acc);
    const int b = row >> 10, n = row & 1023;
    const float c1 = rdb[hh] * LOG2E * (1.0f + ds[(size_t)row * 16 + hh]);
    const float dx = dn[(size_t)row * 4], dy = dn[(size_t)row * 4 + 1], dz = dn[(size_t)row * 4 + 2];
    bf16x8 z = {};
    bf16x8 q0 = z, k0 = z;
    q0[0] = (bf16)(dx * c1); q0[1] = (bf16)(dy * c1); q0[2] = (bf16)(dz * c1); q0[3] = (bf16)1.0f;
    k0[0] = (bf16)dx; k0[1] = (bf16)dy; k0[2] = (bf16)dz; k0[3] = (bf16)(gbv * LOG2E);
    const size_t g = (size_t)(b * 16 + hh) * 1024 + n;
    bf16x8* qp = reinterpret_cast<bf16x8*>(qe + g * 32);
    bf16x8* kp = reinterpret_cast<bf16x8*>(ke + g * 32);
    qp[0] = q0; qp[1] = z; qp[2] = z; qp[3] = z;
    kp[0] = k0; kp[1] = z; kp[2] = z; kp[3] = z;
}

__global__ __launch_bounds__(256) void gemm_k(GJob P)
{
    __shared__ char smem[49152];
    gemm_body(P, blockIdx.x % P.gx, blockIdx.x / P.gx, smem);
}

// ===== pl23m (0-63) || qkv (64-1599) ==
__global__ __launch_bounds__(256) void qkvpl_k(GJob P,
    const bf16* __restrict__ h1, const bf16* __restrict__ w2T, const float* __restrict__ b2,
    const bf16* __restrict__ w3T, const float* __restrict__ b3,
    float* __restrict__ pp, bf16* __restrict__ ppb)
{
    __shared__ char smem[49152];
    if (blockIdx.x < 64) pl23m_body(blockIdx.x, h1, w2T, b2, w3T, b3, pp, ppb, smem);
    else {
        int id = blockIdx.x - 64;
        gemm_body(P, id % P.gx, id / P.gx, smem);
    }
}

// ===== step 4: gb1 (0-255) || wsc combine (256-383) || wcg combine (384-511) =====
// machine is 2/3 idle during gb1 alone — combines ride for ~free (R27 move).
__global__ __launch_bounds__(256) void gemm3_k(GJob P0, GJob P1, GJob P2)
{
    __shared__ char smem[49152];
    int id = blockIdx.x;
    if (id < 256) gemm_body(P0, id % P0.gx, id / P0.gx, smem);
    else if (id < 384) {
        id -= 256;
        gemm_body(P1, id % P1.gx, id / P1.gx, smem);
    } else {
        id -= 384;
        gemm_body(P2, id % P2.gx, id / P2.gx, smem);
    }
}

// ============ gb2x (0-255) || cq GEMM (256-767) || kcv GEMM (768-1791) ============
__global__ __launch_bounds__(256) void gemm2gb_k(GJob P0, GJob P1,
    const bf16* __restrict__ h, const float* __restrict__ w2, const float* __restrict__ b2,
    const float* __restrict__ dn, const float* __restrict__ ds, const float* __restrict__ rdb,
    bf16* __restrict__ qe, bf16* __restrict__ ke)
{
    __shared__ char smem[49152];
    int id = blockIdx.x;
    if (id < 256) gb2x_body(id, h, w2, b2, dn, ds, rdb, qe, ke, smem);
    else if (id < 768) {
        id -= 256;
        gemm_body(P0, id % P0.gx, id / P0.gx, smem);
    } else {
        id -= 768;
        gemm_body(P1, id % P1.gx, id / P1.gx, smem);
    }
}

// ============ XCD-aware block decomposition for attention (512 blocks) ============
__device__ __forceinline__ void attn_bid(int bid, int& bh, int& r0t) {
    const int xcd = bid & 7, s = bid >> 3;
    bh = (s >> 3) * 8 + xcd;
    r0t = s & 7;
}

// ============ MFMA flash self-attention (512 blocks) || spatial diffs (1024 blocks) ======
__global__ __launch_bounds__(512) void attnsd_k(
    const bf16* __restrict__ qb, const bf16* __restrict__ kb, const bf16* __restrict__ vtb,
    const float* __restrict__ relT, bf16* __restrict__ sab,
    const float* __restrict__ pp, bf16* __restrict__ sd)
{
    __shared__ bf16 Ks[2][64 * 64];
    __shared__ bf16 Vs[2][80 * 64];
    __shared__ bf16 Ps[128 * 64];
    __shared__ float relb[2][320];
    const int t = threadIdx.x, w = t >> 6, lane = t & 63;
    if (blockIdx.x >= 512) {
        int g = (blockIdx.x - 512) * 512 + t;
        if (g < B_ * N_ * PP_) {
            const int c = g & 127;
            const int rown = g >> 7;
            const int n = rown & (N_ - 1);
            const int xx = n & 31, yy = (n >> 5) & 31;
            const float cur = pp[g];
            const float hd = (xx < 31) ? fabsf(pp[g + PP_] - cur) : 0.f;
            const float vd = (yy < 31) ? fabsf(pp[g + 32 * PP_] - cur) : 0.f;
            sd[(size_t)rown * 256 + c] = (bf16)hd;
            sd[(size_t)rown * 256 + 128 + c] = (bf16)vd;
        }
        return;
    }
    int bh, r0t;
    attn_bid(blockIdx.x, bh, r0t);
    const int b = bh >> 4, h = bh & 15, r0 = r0t * 128;
    const float* relTh = relT + h * 3969;
    const int y0 = r0 >> 5;

    {   // stage Q (128 rows x 128B) into Ps temp
        const bf16* g = qb + ((size_t)bh * 1024 + r0) * 64;
        #pragma unroll
        for (int r = 0; r < 2; ++r) {
            int i = r * 512 + t;
            int row = i >> 3, c = i & 7;
            const char* src = (const char*)g + (size_t)row * 128 + ((c ^ (row & 7)) << 4);
            gload16(src, Ps + (size_t)(r * 512 + (t & 448)) * 8);
        }
    }
    __syncthreads();
    bf16x8 aq[2];
    {
        const int qr = w * 16 + (lane & 15);
        aq[0] = lds8_swz(Ps, qr, (lane >> 4) * 16);
        aq[1] = lds8_swz(Ps, qr, 64 + (lane >> 4) * 16);
    }
    for (int i = t; i < 2048; i += 512) {
        int buf = i >> 10, idx = i & 1023;
        int row = 64 + (idx >> 6), col = idx & 63;
        Vs[buf][row * 64 + col] = (row == 64) ? (bf16)1.0f : (bf16)0.0f;
    }
    __syncthreads();
    stage64(kb + (size_t)bh * 65536, 128, Ks[0], t);
    stage64(vtb + (size_t)bh * 65536, 2048, Vs[0], t);
    if (t < 320) relb[0][t] = LOG2E * relTh[(y0 + 30 + (t >> 6)) * 63 + min(t & 63, 62)];

    float m_run[4];
    f32x4 of[4], ofe;
    #pragma unroll
    for (int j = 0; j < 4; ++j) m_run[j] = -3e38f;
    #pragma unroll
    for (int dt = 0; dt < 4; ++dt) of[dt] = (f32x4){0.f, 0.f, 0.f, 0.f};
    ofe = (f32x4){0.f, 0.f, 0.f, 0.f};

    const int qrow_lo = (lane >> 4) * 4;
    int dybase[4];
    #pragma unroll
    for (int j = 0; j < 4; ++j) {
        int qg = r0 + w * 16 + qrow_lo + j;
        dybase[j] = (((qg >> 5) - y0) + 1) * 64 + (qg & 31) + 31;
    }
    __syncthreads();

    int cur = 0;
    for (int mt = 0; mt < 16; ++mt) {
        if (mt < 15) {
            stage64(kb + (size_t)bh * 65536 + (size_t)(mt + 1) * 64 * 64, 128, Ks[cur ^ 1], t);
            stage64(vtb + (size_t)bh * 65536 + (size_t)(mt + 1) * 64, 2048, Vs[cur ^ 1], t);
            if (t < 320)
                relb[cur ^ 1][t] = LOG2E * relTh[(y0 - 2 * (mt + 1) + 30 + (t >> 6)) * 63 + min(t & 63, 62)];
        }
        f32x4 sf[4];
        __builtin_amdgcn_s_setprio(1);
        #pragma unroll
        for (int ct = 0; ct < 4; ++ct) {
            const int kr = ct * 16 + (lane & 15);
            f32x4 a = (f32x4){0.f, 0.f, 0.f, 0.f};
            a = MFMA_BF16(aq[0], lds8_swz(Ks[cur], kr, (lane >> 4) * 16), a);
            a = MFMA_BF16(aq[1], lds8_swz(Ks[cur], kr, 64 + (lane >> 4) * 16), a);
            sf[ct] = a;
        }
        __builtin_amdgcn_s_setprio(0);
        float p[4][4], lmax[4];
        #pragma unroll
        for (int j = 0; j < 4; ++j) lmax[j] = -3e38f;
        #pragma unroll
        for (int ct = 0; ct < 4; ++ct) {
            const int xm = (ct & 1) * 16 + (lane & 15);
            const int ro = (ct >> 1) * 64 + xm;
            #pragma unroll
            for (int j = 0; j < 4; ++j) {
                float s = sf[ct][j] + relb[cur][dybase[j] - ro];
                p[ct][j] = s;
                lmax[j] = fmaxf(lmax[j], s);
            }
        }
        bool need = false;
        #pragma unroll
        for (int j = 0; j < 4; ++j) need |= (lmax[j] > m_run[j] + 8.0f);
        if (__any(need)) {
            float mx[4], alpha[4];
            #pragma unroll
            for (int j = 0; j < 4; ++j) mx[j] = lmax[j];
            #pragma unroll
            for (int d = 1; d < 16; d <<= 1)
                #pragma unroll
                for (int j = 0; j < 4; ++j) mx[j] = fmaxf(mx[j], __shfl_xor(mx[j], d));
            #pragma unroll
            for (int j = 0; j < 4; ++j) {
                float mn = fmaxf(m_run[j], mx[j]);
                alpha[j] = exp2f(m_run[j] - mn);
                m_run[j] = mn;
            }
            #pragma unroll
            for (int dt = 0; dt < 4; ++dt)
                #pragma unroll
                for (int j = 0; j < 4; ++j) of[dt][j] *= alpha[j];
            #pragma unroll
            for (int j = 0; j < 4; ++j) ofe[j] *= alpha[j];
        }
        #pragma unroll
        for (int ct = 0; ct < 4; ++ct)
            #pragma unroll
            for (int j = 0; j < 4; ++j)
                p[ct][j] = exp2f(p[ct][j] - m_run[j]);
        #pragma unroll
        for (int ct = 0; ct < 4; ++ct)
            #pragma unroll
            for (int j = 0; j < 4; ++j) {
                const int prow = w * 16 + qrow_lo + j;
                const int ch = (ct * 2 + ((lane & 15) >> 3)) ^ (prow & 7);
                *reinterpret_cast<bf16*>((char*)Ps + prow * 128 + (ch << 4) + (lane & 7) * 2)
                    = (bf16)p[ct][j];
            }
        asm volatile("s_waitcnt lgkmcnt(0)" ::: "memory");
        __builtin_amdgcn_sched_barrier(0);
        bf16x8 ap0 = lds8_swz(Ps, w * 16 + (lane & 15), (lane >> 4) * 16);
        bf16x8 ap1 = lds8_swz(Ps, w * 16 + (lane & 15), 64 + (lane >> 4) * 16);
        __builtin_amdgcn_s_setprio(1);
        #pragma unroll
        for (int dt = 0; dt < 4; ++dt) {
            const int vr = dt * 16 + (lane & 15);
            of[dt] = MFMA_BF16(ap0, lds8_swz(Vs[cur], vr, (lane >> 4) * 16), of[dt]);
            of[dt] = MFMA_BF16(ap1, lds8_swz(Vs[cur], vr, 64 + (lane >> 4) * 16), of[dt]);
        }
        {
            const int vr = 64 + (lane & 15);
            ofe = MFMA_BF16(ap0, lds8_swz(Vs[cur], vr, (lane >> 4) * 16), ofe);
            ofe = MFMA_BF16(ap1, lds8_swz(Vs[cur], vr, 64 + (lane >> 4) * 16), ofe);
        }
        __builtin_amdgcn_s_setprio(0);
        __syncthreads();
        cur ^= 1;
    }
    float inv[4];
    #pragma unroll
    for (int j = 0; j < 4; ++j) inv[j] = 1.f / __shfl(ofe[j], lane & 48);
    #pragma unroll
    for (int dt = 0; dt < 4; ++dt)
        #pragma unroll
        for (int j = 0; j < 4; ++j)
            sab[((size_t)(b * N_ + r0 + w * 16 + qrow_lo + j)) * C_ + h * 64 + dt * 16 + (lane & 15)] =
                (bf16)(of[dt][j] * inv[j]);
}

// ============ MFMA flash cross-attention, ext-K folded biases, lazy softmax ============
__global__ __launch_bounds__(512) void attn_cross_m(
    const bf16* __restrict__ cq, const bf16* __restrict__ qe,
    const bf16* __restrict__ ck, const bf16* __restrict__ ke,
    const bf16* __restrict__ cvt, bf16* __restrict__ cob)
{
    __shared__ bf16 Ks[2][64 * 64];
    __shared__ bf16 Ke[2][32 * 64];
    __shared__ bf16 Vs[2][80 * 64];
    __shared__ bf16 Ps[128 * 64];
    const int t = threadIdx.x, w = t >> 6, lane = t & 63;
    int bh, r0t;
    attn_bid(blockIdx.x, bh, r0t);
    const int b = bh >> 4, h = bh & 15, r0 = r0t * 128;

    {   // stage Q main (128 rows x 128B) into Ps temp
        const bf16* g = cq + ((size_t)bh * 1024 + r0) * 64;
        #pragma unroll
        for (int r = 0; r < 2; ++r) {
            int i = r * 512 + t;
            int row = i >> 3, c = i & 7;
            const char* src = (const char*)g + (size_t)row * 128 + ((c ^ (row & 7)) << 4);
            gload16(src, Ps + (size_t)(r * 512 + (t & 448)) * 8);
        }
    }
    stage64(qe + ((size_t)bh * 1024 + r0) * 32, 128, Ks[0], t);
    __syncthreads();
    bf16x8 aq[2], aqe;
    {
        const int qr = w * 16 + (lane & 15);
        aq[0] = lds8_swz(Ps, qr, (lane >> 4) * 16);
        aq[1] = lds8_swz(Ps, qr, 64 + (lane >> 4) * 16);
        aqe = lds8_ke(Ks[0], qr, lane >> 4);
    }
    for (int i = t; i < 2048; i += 512) {
        int buf = i >> 10, idx = i & 1023;
        int row = 64 + (idx >> 6), col = idx & 63;
        Vs[buf][row * 64 + col] = (row == 64) ? (bf16)1.0f : (bf16)0.0f;
    }
    __syncthreads();
    stage64(ck + (size_t)bh * 65536, 128, Ks[0], t);
    stage32(ke + (size_t)bh * 32768, Ke[0], t);
    stage64(cvt + (size_t)bh * 65536, 2048, Vs[0], t);

    float m_run[4];
    f32x4 of[4], ofe;
    #pragma unroll
    for (int j = 0; j < 4; ++j) m_run[j] = -3e38f;
    #pragma unroll
    for (int dt = 0; dt < 4; ++dt) of[dt] = (f32x4){0.f, 0.f, 0.f, 0.f};
    ofe = (f32x4){0.f, 0.f, 0.f, 0.f};
    const int qrow_lo = (lane >> 4) * 4;
    __syncthreads();

    int cur = 0;
    for (int mt = 0; mt < 16; ++mt) {
        if (mt < 15) {
            stage64(ck + (size_t)bh * 65536 + (size_t)(mt + 1) * 64 * 64, 128, Ks[cur ^ 1], t);
            stage32(ke + (size_t)bh * 32768 + (size_t)(mt + 1) * 64 * 32, Ke[cur ^ 1], t);
            stage64(cvt + (size_t)bh * 65536 + (size_t)(mt + 1) * 64, 2048, Vs[cur ^ 1], t);
        }
        f32x4 sf[4];
        __builtin_amdgcn_s_setprio(1);
        #pragma unroll
        for (int ct = 0; ct < 4; ++ct) {
            const int kr = ct * 16 + (lane & 15);
            f32x4 a = (f32x4){0.f, 0.f, 0.f, 0.f};
            a = MFMA_BF16(aq[0], lds8_swz(Ks[cur], kr, (lane >> 4) * 16), a);
            a = MFMA_BF16(aq[1], lds8_swz(Ks[cur], kr, 64 + (lane >> 4) * 16), a);
            a = MFMA_BF16(aqe, lds8_ke(Ke[cur], kr, lane >> 4), a);
            sf[ct] = a;
        }
        __builtin_amdgcn_s_setprio(0);
        float lmax[4];
        #pragma unroll
        for (int j = 0; j < 4; ++j)
            lmax[j] = fmaxf(fmaxf(sf[0][j], sf[1][j]), fmaxf(sf[2][j], sf[3][j]));
        bool need = false;
        #pragma unroll
        for (int j = 0; j < 4; ++j) need |= (lmax[j] > m_run[j] + 8.0f);
        if (__any(need)) {
            float mx[4], alpha[4];
            #pragma unroll
            for (int j = 0; j < 4; ++j) mx[j] = lmax[j];
            #pragma unroll
            for (int d = 1; d < 16; d <<= 1)
                #pragma unroll
                for (int j = 0; j < 4; ++j) mx[j] = fmaxf(mx[j], __shfl_xor(mx[j], d));
            #pragma unroll
            for (int j = 0; j < 4; ++j) {
                float mn = fmaxf(m_run[j], mx[j]);
                alpha[j] = exp2f(m_run[j] - mn);
                m_run[j] = mn;
            }
            #pragma unroll
            for (int dt = 0; dt < 4; ++dt)
                #pragma unroll
                for (int j = 0; j < 4; ++j) of[dt][j] *= alpha[j];
            #pragma unroll
            for (int j = 0; j < 4; ++j) ofe[j] *= alpha[j];
        }
        #pragma unroll
        for (int ct = 0; ct < 4; ++ct)
            #pragma unroll
            for (int j = 0; j < 4; ++j)
                sf[ct][j] = exp2f(sf[ct][j] - m_run[j]);
        #pragma unroll
        for (int ct = 0; ct < 4; ++ct)
            #pragma unroll
            for (int j = 0; j < 4; ++j) {
                const int prow = w * 16 + qrow_lo + j;
                const int ch = (ct * 2 + ((lane & 15) >> 3)) ^ (prow & 7);
                *reinterpret_cast<bf16*>((char*)Ps + prow * 128 + (ch << 4) + (lane & 7) * 2)
                    = (bf16)sf[ct][j];
            }
        asm volatile("s_waitcnt lgkmcnt(0)" ::: "memory");
        __builtin_amdgcn_sched_barrier(0);
        bf16x8 ap0 = lds8_swz(Ps, w * 16 + (lane & 15), (lane >> 4) * 16);
        bf16x8 ap1 = lds8_swz(Ps, w * 16 + (lane & 15), 64 + (lane >> 4) * 16);
        __builtin_amdgcn_s_setprio(1);
        #pragma unroll
        for (int dt = 0; dt < 4; ++dt) {
            const int vr = dt * 16 + (lane & 15);
            of[dt] = MFMA_BF16(ap0, lds8_swz(Vs[cur], vr, (lane >> 4) * 16), of[dt]);
            of[dt] = MFMA_BF16(ap1, lds8_swz(Vs[cur], vr, 64 + (lane >> 4) * 16), of[dt]);
        }
        {
            const int vr = 64 + (lane & 15);
            ofe = MFMA_BF16(ap0, lds8_swz(Vs[cur], vr, (lane >> 4) * 16), ofe);
            ofe = MFMA_BF16(ap1, lds8_swz(Vs[cur], vr, 64 + (lane >> 4) * 16), ofe);
        }
        __builtin_amdgcn_s_setprio(0);
        __syncthreads();
        cur ^= 1;
    }
    float inv[4];
    #pragma unroll
    for (int j = 0; j < 4; ++j) inv[j] = 1.f / __shfl(ofe[j], lane & 48);
    #pragma unroll
    for (int dt = 0; dt < 4; ++dt)
        #pragma unroll
        for (int j = 0; j < 4; ++j)
            cob[((size_t)(b * N_ + r0 + w * 16 + qrow_lo + j)) * C_ + h * 64 + dt * 16 + (lane & 15)] =
                (bf16)(of[dt][j] * inv[j]);
}

extern "C" void kernel_launch(void* const* d_in, const int* in_sizes, int n_in,
                              void* d_out, int out_size, void* d_ws, size_t ws_size,
                              hipStream_t stream)
{
    const float* x     = (const float*)d_in[0];
    const float* pl    = (const float*)d_in[1];
    const float* w_qkv = (const float*)d_in[2];
    const float* w_sp  = (const float*)d_in[3];
    const float* b_sp  = (const float*)d_in[4];
    const float* pl_w1 = (const float*)d_in[5];
    const float* pl_b1 = (const float*)d_in[6];
    const float* pl_w2 = (const float*)d_in[7];
    const float* pl_b2 = (const float*)d_in[8];
    const float* pl_w3 = (const float*)d_in[9];
    const float* pl_b3 = (const float*)d_in[10];
    const float* w_cq  = (const float*)d_in[11];
    const float* w_pk  = (const float*)d_in[12];
    const float* w_pv  = (const float*)d_in[13];
    const float* w_cp  = (const float*)d_in[14];
    const float* b_cp  = (const float*)d_in[15];
    const float* rdb   = (const float*)d_in[16];
    const float* ds_w1 = (const float*)d_in[17];
    const float* ds_b1 = (const float*)d_in[18];
    const float* ds_w2 = (const float*)d_in[19];
    const float* ds_b2 = (const float*)d_in[20];
    const float* gb_w1 = (const float*)d_in[21];
    const float* gb_b1 = (const float*)d_in[22];
    const float* gb_w2 = (const float*)d_in[23];
    const float* gb_b2 = (const float*)d_in[24];
    const float* rel_t = (const float*)d_in[25];
    const float* gfw1  = (const float*)d_in[26];
    const float* gfb1  = (const float*)d_in[27];
    const float* gfw2  = (const float*)d_in[28];
    const float* gfb2  = (const float*)d_in[29];

    char* W = (char*)d_ws;
    float* out = (float*)d_out;
    const size_t MB = 1ull << 20;
    const size_t KB = 1024;

    bf16* qb     = (bf16*)(W + 0);           // 8MB ; cqb reuses
    bf16* kb     = (bf16*)(W + 8 * MB);      // 8MB ; ckb reuses
    bf16* vtb    = (bf16*)(W + 16 * MB);     // 8MB ; cvtb reuses
    bf16* cqb    = qb;
    bf16* ckb    = kb;
    bf16* cvtb   = vtb;
    bf16* xb     = (bf16*)(W + 24 * MB);     // 8MB
    bf16* wqkvT  = (bf16*)(W + 32 * MB);     // 6MB
    bf16* wspB   = (bf16*)(W + 38 * MB);     // 2MB (plain cast of w_sp)
    bf16* wcqT   = (bf16*)(W + 40 * MB);     // 2MB
    bf16* wpkT   = (bf16*)(W + 42 * MB);               // 256KB
    bf16* wpvT   = (bf16*)(W + 42 * MB + 256 * KB);    // 256KB (contiguous after wpkT)
    bf16* wcpB   = (bf16*)(W + 43 * MB);     // 2MB (plain cast of w_cp)
    bf16* gf1tT  = (bf16*)(W + 45 * MB);     // 2MB (gfw1 top 1024 rows, transposed)
    bf16* gf1bT  = (bf16*)(W + 47 * MB);     // 256KB (gfw1 bottom 128 rows, transposed)
    bf16* gfw2T  = (bf16*)(W + 48 * MB);     // 2MB
    bf16* gbw1T  = (bf16*)(W + 50 * MB);               // 256KB
    bf16* plw2T  = (bf16*)(W + 50 * MB + 256 * KB);    // 64KB
    bf16* plw3T  = (bf16*)(W + 50 * MB + 320 * KB);    // 32KB
    bf16* sab    = (bf16*)(W + 51 * MB);     // 8MB ; cob reuses
    bf16* cob    = sab;
    float* pp    = (float*)(W + 67 * MB);    // 2MB
    bf16* ppb    = (bf16*)(W + 69 * MB);     // 1MB
    bf16* sdb16  = (bf16*)(W + 70 * MB);     // 2MB
    bf16* h1b    = (bf16*)(W + 72 * MB);     // 2MB
    bf16* gbh    = (bf16*)(W + 75 * MB);     // 4MB
    float* dsb   = (float*)(W + 79 * MB);              // 256KB
    float* dnb   = (float*)(W + 79 * MB + 256 * KB);   // 64KB
    float2* rtab = (float2*)(W + 80 * MB);             // 256KB
    float* relTb = (float*)(W + 80 * MB + 256 * KB);   // 254KB
    bf16* hidb   = (bf16*)(W + 81 * MB);     // 8MB
    bf16* qeb    = (bf16*)(W + 89 * MB);     // 4MB [64][1024][32]
    bf16* keb    = (bf16*)(W + 93 * MB);     // 4MB
    bf16* wcgT   = (bf16*)(W + 97 * MB);     // 2MB (combined (w_cp@gfw1_top)^T)
    float* bscgb = (float*)(W + 99 * MB);              // 4KB
    float* bscb  = (float*)(W + 99 * MB + 8 * KB);     // 4KB
    bf16* wscT   = (bf16*)(W + 100 * MB);    // 2MB (combined (w_sp@w_cq)^T) -> 102MB total

    const dim3 blk(256);

    TJobs J;
    J.src[0] = w_qkv;              J.dst[0] = wqkvT; J.K[0] = 1024; J.N[0] = 3072;
    J.src[1] = w_cq;               J.dst[1] = wcqT;  J.K[1] = 1024; J.N[1] = 1024;
    J.src[2] = w_pk;               J.dst[2] = wpkT;  J.K[2] = 128;  J.N[2] = 1024;
    J.src[3] = w_pv;               J.dst[3] = wpvT;  J.K[3] = 128;  J.N[3] = 1024;
    J.src[4] = gfw1;               J.dst[4] = gf1tT; J.K[4] = 1024; J.N[4] = 1024;
    J.src[5] = gfw1 + 1024 * 1024; J.dst[5] = gf1bT; J.K[5] = 128;  J.N[5] = 1024;
    J.src[6] = gfw2;               J.dst[6] = gfw2T; J.K[6] = 1024; J.N[6] = 1024;
    J.src[7] = gb_w1;              J.dst[7] = gbw1T; J.K[7] = 256;  J.N[7] = 512;
    J.src[8] = pl_w2;              J.dst[8] = plw2T; J.K[8] = 256;  J.N[8] = 128;
    J.src[9] = pl_w3;              J.dst[9] = plw3T; J.K[9] = 128;  J.N[9] = 128;
    {
        int acc = 0;
        for (int j = 0; j < 10; ++j) {
            J.base[j] = acc;
            acc += (J.N[j] >> 5) * (J.K[j] >> 5);
        }
        J.base[10] = acc;
    }
    const int pre_blocks = J.base[10] + 4096 + 512 + 377 + 32 + 1024;

    auto mkjob = [](const bf16* A, const bf16* A2, const bf16* Bt, const bf16* Bt2,
                    const float* bias, const float* resid,
                    void* o0, void* o1, void* o2, const float2* rt,
                    int N, int K, int K1A, int K1B, int epi, int ag, int gx, float sc) {
        GJob g;
        g.A = A; g.A2 = A2; g.Bt = Bt; g.Bt2 = Bt2; g.bias = bias; g.resid = resid;
        g.out0 = o0; g.out1 = o1; g.out2 = o2; g.rtab = rt;
        g.N = N; g.K = K; g.K1A = K1A; g.K1B = K1B; g.epi = epi; g.act_gelu = ag;
        g.gx = gx; g.scale = sc;
        return g;
    };

    // 1. merged preamble (+ w_cp/w_sp casts + bscg/bsc GEMVs)
    pre_k<<<pre_blocks, blk, 0, stream>>>(J, x, xb, w_cp, wcpB, w_sp, wspB,
        rel_t, relTb, rtab, b_cp, gfw1, gfb1, bscgb, b_sp, w_cq, bscb,
        pl, pl_w1, pl_b1, ds_w1, ds_b1, ds_w2, ds_b2, h1b, dsb, dnb);
    // 2. pl23m || qkv GEMM (combines moved to step 4's idle capacity)
    GJob jqkv = mkjob(xb, nullptr, wqkvT, nullptr, nullptr, nullptr,
                      qb, kb, vtb, rtab, 3072, 1024, 1024, 1024, 2, 0, 48, 0.125f * LOG2E);
    qkvpl_k<<<64 + 1536, blk, 0, stream>>>(jqkv,
        h1b, plw2T, pl_b2, plw3T, pl_b3, pp, ppb);
    // 3. self attention || spatial diffs
    attnsd_k<<<512 + 1024, dim3(512), 0, stream>>>(qb, kb, vtb, relTb, sab, pp, sdb16);
    // 4. tri GEMM: gb layer1 (gelu) || wsc combine || wcg combine (machine 2/3 idle)
    GJob jgb1 = mkjob(sdb16, nullptr, gbw1T, nullptr, gb_b1, nullptr,
                      gbh, nullptr, nullptr, nullptr, 512, 256, 256, 256, 1, 1, 8, 1.f);
    GJob jwsc = mkjob(wcqT, nullptr, wspB, nullptr, nullptr, nullptr,
                      wscT, nullptr, nullptr, nullptr, 1024, 1024, 1024, 1024, 1, 0, 16, 1.f);
    GJob jwcg = mkjob(gf1tT, nullptr, wcpB, nullptr, nullptr, nullptr,
                      wcgT, nullptr, nullptr, nullptr, 1024, 1024, 1024, 1024, 1, 0, 16, 1.f);
    gemm3_k<<<256 + 128 + 128, blk, 0, stream>>>(jgb1, jwsc, jwcg);
    // 5. tri launch: gb2x first, then cq = rope(sa@wsc + bsc)*(dsr scale) || ck+cv split
    GJob jcq  = mkjob(sab, nullptr, wscT, nullptr, bscb, dsb,
                      cqb, nullptr, nullptr, rtab, 1024, 1024, 1024, 1024, 6, 0, 16, 0.125f * LOG2E);
    GJob jkcv = mkjob(ppb, nullptr, wpkT, nullptr, nullptr, nullptr,
                      ckb, nullptr, cvtb, rtab, 2048, 128, 128, 128, 7, 0, 32, 1.f);
    gemm2gb_k<<<256 + 512 + 1024, blk, 0, stream>>>(jcq, jkcv,
        gbh, gb_w2, gb_b2, dnb, dsb, rdb, qeb, keb);
    // 6. cross attention
    attn_cross_m<<<512, dim3(512), 0, stream>>>(cqb, qeb, ckb, keb, cvtb, cob);
    // 7. gfe1 with folded cross-proj: gelu(cob@wcgT^T + pp@gf1bT^T + bscg)
    GJob jg1 = mkjob(cob, ppb, wcgT, gf1bT, bscgb, nullptr,
                     hidb, nullptr, nullptr, nullptr, 1024, 1152, 1024, 1024, 1, 1, 16, 1.f);
    gemm_k<<<512, blk, 0, stream>>>(jg1);
    // 8. gfe2 + bias + residual -> fp32 out
    GJob jg2 = mkjob(hidb, nullptr, gfw2T, nullptr, gfb2, x,
                     out, nullptr, nullptr, nullptr, 1024, 1024, 1024, 1024, 0, 0, 16, 1.f);
    gemm_k<<<512, blk, 0, stream>>>(jg2);
}